// Round 1
// baseline (4312.620 us; speedup 1.0000x reference)
//
#include <hip/hip_runtime.h>
#include <math.h>

#define BDIM 2
#define SDIM 2048
#define HIDD 2048
#define NHH 16
#define HDD 128
#define QKDD 64
#define MTOT (BDIM*SDIM)   // 4096

__device__ __constant__ float d_const_unused[1];

constexpr float LAMBDA_INIT_F = 0.3555090675909693f;  // 0.8 - 0.6*exp(-0.3)
constexpr float EPS_F = 1e-6f;
constexpr float SCALE_F = 0.125f;                     // 1/sqrt(64)

// ---------------------------------------------------------------- lambda ----
__global__ void lambda_kernel(const float* __restrict__ lq1, const float* __restrict__ lk1,
                              const float* __restrict__ lq2, const float* __restrict__ lk2,
                              float* __restrict__ lam_out) {
    int l = threadIdx.x;  // 64 threads, 1 wave
    float d1 = lq1[l] * lk1[l] + lq1[l + 64] * lk1[l + 64];
    float d2 = lq2[l] * lk2[l] + lq2[l + 64] * lk2[l + 64];
#pragma unroll
    for (int o = 32; o > 0; o >>= 1) {
        d1 += __shfl_down(d1, o);
        d2 += __shfl_down(d2, o);
    }
    if (l == 0) lam_out[0] = expf(d1) - expf(d2) + LAMBDA_INIT_F;
}

// ------------------------------------------------------------------- GEMM ---
// C[M,N] = X[M,K] @ W[N,K]^T   (torch Linear with row-major weight)
__global__ __launch_bounds__(256) void gemm_xwt(const float* __restrict__ X,
                                                const float* __restrict__ W,
                                                float* __restrict__ C,
                                                int M, int N, int K) {
    __shared__ float As[16][68];  // As[kk][m]
    __shared__ float Bs[16][68];  // Bs[kk][n]
    const int tid = threadIdx.x;
    const int tr = tid & 15;      // output row group
    const int tc = tid >> 4;      // output col group
    const int bm = blockIdx.y * 64;
    const int bn = blockIdx.x * 64;

    float acc[4][4] = {};

    for (int k0 = 0; k0 < K; k0 += 16) {
        {
            const int m   = tid >> 2;           // 0..63
            const int kk4 = (tid & 3) * 4;      // 0,4,8,12
            float4 va = *(const float4*)&X[(size_t)(bm + m) * K + k0 + kk4];
            As[kk4 + 0][m] = va.x; As[kk4 + 1][m] = va.y;
            As[kk4 + 2][m] = va.z; As[kk4 + 3][m] = va.w;
            float4 vb = *(const float4*)&W[(size_t)(bn + m) * K + k0 + kk4];
            Bs[kk4 + 0][m] = vb.x; Bs[kk4 + 1][m] = vb.y;
            Bs[kk4 + 2][m] = vb.z; Bs[kk4 + 3][m] = vb.w;
        }
        __syncthreads();
#pragma unroll
        for (int kk = 0; kk < 16; ++kk) {
            float4 a = *(const float4*)&As[kk][tr * 4];
            float4 b = *(const float4*)&Bs[kk][tc * 4];
            float av[4] = {a.x, a.y, a.z, a.w};
            float bv[4] = {b.x, b.y, b.z, b.w};
#pragma unroll
            for (int i = 0; i < 4; ++i)
#pragma unroll
                for (int j = 0; j < 4; ++j) acc[i][j] += av[i] * bv[j];
        }
        __syncthreads();
    }
#pragma unroll
    for (int i = 0; i < 4; ++i) {
        float4 o = make_float4(acc[i][0], acc[i][1], acc[i][2], acc[i][3]);
        *(float4*)&C[(size_t)(bm + tr * 4 + i) * N + bn + tc * 4] = o;
    }
}

// ------------------------------------------------------------------- RoPE ---
// In-place interleaved RoPE on projected Q and K.
// Channel layout per row: h*128 + g*64 + c, rotate pairs (2i, 2i+1), table at [s, 2i].
__global__ void rope_kernel(float* __restrict__ Qp, float* __restrict__ Kp,
                            const float* __restrict__ cosE, const float* __restrict__ sinE) {
    int idx = blockIdx.x * blockDim.x + threadIdx.x;  // pairs: B*S*NH*2*32
    if (idx >= BDIM * SDIM * NHH * 2 * 32) return;
    int i = idx & 31;  idx >>= 5;   // pair index
    int g = idx & 1;   idx >>= 1;   // q1/q2 half
    int h = idx & 15;  idx >>= 4;   // head
    int s = idx & (SDIM - 1);
    int b = idx >> 11;
    size_t base = ((size_t)(b * SDIM + s)) * HIDD + h * HDD + g * QKDD + 2 * i;
    float c  = cosE[s * HDD + 2 * i];
    float sn = sinE[s * HDD + 2 * i];
    float x0 = Qp[base], x1 = Qp[base + 1];
    Qp[base]     = x0 * c - x1 * sn;
    Qp[base + 1] = x1 * c + x0 * sn;
    x0 = Kp[base]; x1 = Kp[base + 1];
    Kp[base]     = x0 * c - x1 * sn;
    Kp[base + 1] = x1 * c + x0 * sn;
}

// ------------------------------------------------------- differential flash -
#define FBM 32
#define FBN 32
__global__ __launch_bounds__(256) void flash_diff(
        const float* __restrict__ Qp, const float* __restrict__ Kp,
        const float* __restrict__ Vp, const float* __restrict__ gnw,
        const float* __restrict__ lam_p, float* __restrict__ Hout) {
    __shared__ float Qs[FBM][132];
    __shared__ float Ks[FBN][132];
    __shared__ float Vs[FBN][128];
    __shared__ float Ps[2][FBM][FBN + 1];

    const int tid = threadIdx.x;
    const int m  = tid >> 3;  // query row in tile 0..31
    const int kq = tid & 7;   // 8 lanes per row
    const int bx = blockIdx.x;
    const int b  = blockIdx.y / NHH;
    const int h  = blockIdx.y % NHH;
    const int s0 = bx * FBM;
    const float lam = lam_p[0];

    // load Q tile: 32 rows x 128 cols (both 64-halves)
#pragma unroll
    for (int r = 0; r < 4; ++r) {
        int fidx = tid + r * 256;
        int row  = fidx >> 5;
        int c4   = (fidx & 31) * 4;
        float4 v = *(const float4*)&Qp[((size_t)(b * SDIM + s0 + row)) * HIDD + h * HDD + c4];
        *(float4*)&Qs[row][c4] = v;
    }

    float M1 = -INFINITY, M2 = -INFINITY, L1 = 0.f, L2 = 0.f;
    float O1[4][4] = {};  // d = jj*32 + kq*4 + r
    float O2[4][4] = {};

    const int ntiles = bx + 1;
    for (int t = 0; t < ntiles; ++t) {
        const int t0 = t * FBN;
        __syncthreads();  // protect Ks/Vs from previous iteration's readers
#pragma unroll
        for (int r = 0; r < 4; ++r) {
            int fidx = tid + r * 256;
            int row  = fidx >> 5;
            int c4   = (fidx & 31) * 4;
            size_t g = ((size_t)(b * SDIM + t0 + row)) * HIDD + h * HDD + c4;
            float4 kv = *(const float4*)&Kp[g];
            *(float4*)&Ks[row][c4] = kv;
            float4 vv = *(const float4*)&Vp[g];
            *(float4*)&Vs[row][c4] = vv;
        }
        __syncthreads();

        // ---- scores for 4 keys per thread: n = kq + j*8 (interleaved) ----
        float s1[4] = {0.f, 0.f, 0.f, 0.f};
        float s2[4] = {0.f, 0.f, 0.f, 0.f};
#pragma unroll
        for (int c4 = 0; c4 < QKDD; c4 += 4) {
            float4 q1 = *(const float4*)&Qs[m][c4];
            float4 q2 = *(const float4*)&Qs[m][64 + c4];
#pragma unroll
            for (int j = 0; j < 4; ++j) {
                const int n = kq + j * 8;
                float4 ka = *(const float4*)&Ks[n][c4];
                float4 kb = *(const float4*)&Ks[n][64 + c4];
                s1[j] += q1.x * ka.x + q1.y * ka.y + q1.z * ka.z + q1.w * ka.w;
                s2[j] += q2.x * kb.x + q2.y * kb.y + q2.z * kb.z + q2.w * kb.w;
            }
        }
        const int srow = s0 + m;
        float mx1 = -INFINITY, mx2 = -INFINITY;
#pragma unroll
        for (int j = 0; j < 4; ++j) {
            int tcol = t0 + kq + j * 8;
            bool valid = (tcol <= srow);
            s1[j] = valid ? s1[j] * SCALE_F : -INFINITY;
            s2[j] = valid ? s2[j] * SCALE_F : -INFINITY;
            mx1 = fmaxf(mx1, s1[j]);
            mx2 = fmaxf(mx2, s2[j]);
        }
#pragma unroll
        for (int o = 1; o < 8; o <<= 1) {
            mx1 = fmaxf(mx1, __shfl_xor(mx1, o));
            mx2 = fmaxf(mx2, __shfl_xor(mx2, o));
        }
        const float Mn1 = fmaxf(M1, mx1);
        const float Mn2 = fmaxf(M2, mx2);
        const float a1 = expf(M1 - Mn1);
        const float a2 = expf(M2 - Mn2);
        float ps1 = 0.f, ps2 = 0.f;
#pragma unroll
        for (int j = 0; j < 4; ++j) {
            float p1 = expf(s1[j] - Mn1);
            float p2 = expf(s2[j] - Mn2);
            ps1 += p1; ps2 += p2;
            Ps[0][m][kq + j * 8] = p1;
            Ps[1][m][kq + j * 8] = p2;
        }
#pragma unroll
        for (int o = 1; o < 8; o <<= 1) {
            ps1 += __shfl_xor(ps1, o);
            ps2 += __shfl_xor(ps2, o);
        }
        L1 = L1 * a1 + ps1;
        L2 = L2 * a2 + ps2;
        M1 = Mn1; M2 = Mn2;
#pragma unroll
        for (int jj = 0; jj < 4; ++jj)
#pragma unroll
            for (int r = 0; r < 4; ++r) { O1[jj][r] *= a1; O2[jj][r] *= a2; }
        __syncthreads();  // Ps visible

        // ---- PV accumulate: this thread owns d = jj*32 + kq*4 + r ----
        for (int n = 0; n < FBN; ++n) {
            float pp1 = Ps[0][m][n];
            float pp2 = Ps[1][m][n];
#pragma unroll
            for (int jj = 0; jj < 4; ++jj) {
                float4 v = *(const float4*)&Vs[n][jj * 32 + kq * 4];
                O1[jj][0] += pp1 * v.x; O1[jj][1] += pp1 * v.y;
                O1[jj][2] += pp1 * v.z; O1[jj][3] += pp1 * v.w;
                O2[jj][0] += pp2 * v.x; O2[jj][1] += pp2 * v.y;
                O2[jj][2] += pp2 * v.z; O2[jj][3] += pp2 * v.w;
            }
        }
    }

    // ---- epilogue: differential combine + RMSNorm + gnorm scale ----
    const float inv1 = 1.f / L1;
    const float inv2 = lam / L2;
    float od[4][4];
    float ss = 0.f;
#pragma unroll
    for (int jj = 0; jj < 4; ++jj)
#pragma unroll
        for (int r = 0; r < 4; ++r) {
            float o = O1[jj][r] * inv1 - O2[jj][r] * inv2;
            od[jj][r] = o;
            ss += o * o;
        }
#pragma unroll
    for (int o = 1; o < 8; o <<= 1) ss += __shfl_xor(ss, o);
    const float rms = rsqrtf(ss * (1.0f / HDD) + EPS_F);
    const float osc = (1.0f - LAMBDA_INIT_F) * rms;
    const int srow = s0 + m;
    const size_t obase = ((size_t)(b * SDIM + srow)) * HIDD + h * HDD;
#pragma unroll
    for (int jj = 0; jj < 4; ++jj) {
        int d = jj * 32 + kq * 4;
        float4 o = make_float4(od[jj][0] * osc * gnw[d + 0],
                               od[jj][1] * osc * gnw[d + 1],
                               od[jj][2] * osc * gnw[d + 2],
                               od[jj][3] * osc * gnw[d + 3]);
        *(float4*)&Hout[obase + d] = o;
    }
}

// ----------------------------------------------------------------- launch ---
extern "C" void kernel_launch(void* const* d_in, const int* in_sizes, int n_in,
                              void* d_out, int out_size, void* d_ws, size_t ws_size,
                              hipStream_t stream) {
    const float* q   = (const float*)d_in[0];
    const float* k   = (const float*)d_in[1];
    const float* v   = (const float*)d_in[2];
    const float* Wq  = (const float*)d_in[3];
    const float* Wk  = (const float*)d_in[4];
    const float* Wv  = (const float*)d_in[5];
    const float* Wo  = (const float*)d_in[6];
    const float* lq1 = (const float*)d_in[7];
    const float* lk1 = (const float*)d_in[8];
    const float* lq2 = (const float*)d_in[9];
    const float* lk2 = (const float*)d_in[10];
    const float* gnw = (const float*)d_in[11];
    const float* cosE = (const float*)d_in[12];
    const float* sinE = (const float*)d_in[13];
    float* out = (float*)d_out;
    float* ws  = (float*)d_ws;

    const size_t TEN = (size_t)BDIM * SDIM * HIDD;  // 8388608 floats
    float* Qp   = ws;
    float* Kp   = ws + TEN;
    float* Vp   = ws + 2 * TEN;
    float* Ho   = ws + 3 * TEN;
    float* lamp = ws + 4 * TEN;

    lambda_kernel<<<1, 64, 0, stream>>>(lq1, lk1, lq2, lk2, lamp);

    dim3 gg(HIDD / 64, MTOT / 64);
    gemm_xwt<<<gg, 256, 0, stream>>>(q, Wq, Qp, MTOT, HIDD, HIDD);
    gemm_xwt<<<gg, 256, 0, stream>>>(k, Wk, Kp, MTOT, HIDD, HIDD);
    gemm_xwt<<<gg, 256, 0, stream>>>(v, Wv, Vp, MTOT, HIDD, HIDD);

    int pairs = BDIM * SDIM * NHH * 2 * (QKDD / 2);
    rope_kernel<<<(pairs + 255) / 256, 256, 0, stream>>>(Qp, Kp, cosE, sinE);

    dim3 fg(SDIM / FBM, BDIM * NHH);
    flash_diff<<<fg, 256, 0, stream>>>(Qp, Kp, Vp, gnw, lamp, Ho);

    gemm_xwt<<<gg, 256, 0, stream>>>(Ho, Wo, out, MTOT, HIDD, HIDD);
}

// Round 2
// 2104.872 us; speedup vs baseline: 2.0489x; 2.0489x over previous
//
#include <hip/hip_runtime.h>
#include <math.h>

#define BDIM 2
#define SDIM 2048
#define HIDD 2048
#define NHH 16
#define HDD 128
#define QKDD 64
#define MTOT (BDIM*SDIM)   // 4096

constexpr float LAMBDA_INIT_F = 0.3555090675909693f;  // 0.8 - 0.6*exp(-0.3)
constexpr float EPS_F = 1e-6f;
constexpr float SCALE_F = 0.125f;                     // 1/sqrt(64)

typedef float f32x4 __attribute__((ext_vector_type(4)));
typedef short bf16x8 __attribute__((ext_vector_type(8)));

#define MFMA16(a, b, c) __builtin_amdgcn_mfma_f32_16x16x32_bf16((a), (b), (c), 0, 0, 0)

__device__ __forceinline__ short f2bf(float f) {
    unsigned u = __float_as_uint(f);
    u += 0x7FFFu + ((u >> 16) & 1u);   // RNE
    return (short)(u >> 16);
}
__device__ __forceinline__ unsigned pk2(float a, float b) {
    return (unsigned)(unsigned short)f2bf(a) | ((unsigned)(unsigned short)f2bf(b) << 16);
}

// ---------------------------------------------------------------- lambda ----
__global__ void lambda_kernel(const float* __restrict__ lq1, const float* __restrict__ lk1,
                              const float* __restrict__ lq2, const float* __restrict__ lk2,
                              float* __restrict__ lam_out) {
    int l = threadIdx.x;  // 64 threads, 1 wave
    float d1 = lq1[l] * lk1[l] + lq1[l + 64] * lk1[l + 64];
    float d2 = lq2[l] * lk2[l] + lq2[l + 64] * lk2[l + 64];
#pragma unroll
    for (int o = 32; o > 0; o >>= 1) {
        d1 += __shfl_down(d1, o);
        d2 += __shfl_down(d2, o);
    }
    if (l == 0) lam_out[0] = expf(d1) - expf(d2) + LAMBDA_INIT_F;
}

// ------------------------------------------------------------------- GEMM ---
// C[M,N] = X[M,K] @ W[N,K]^T   (fp32, unchanged this round)
__global__ __launch_bounds__(256) void gemm_xwt(const float* __restrict__ X,
                                                const float* __restrict__ W,
                                                float* __restrict__ C,
                                                int M, int N, int K) {
    __shared__ float As[16][68];
    __shared__ float Bs[16][68];
    const int tid = threadIdx.x;
    const int tr = tid & 15;
    const int tc = tid >> 4;
    const int bm = blockIdx.y * 64;
    const int bn = blockIdx.x * 64;

    float acc[4][4] = {};

    for (int k0 = 0; k0 < K; k0 += 16) {
        {
            const int m   = tid >> 2;
            const int kk4 = (tid & 3) * 4;
            float4 va = *(const float4*)&X[(size_t)(bm + m) * K + k0 + kk4];
            As[kk4 + 0][m] = va.x; As[kk4 + 1][m] = va.y;
            As[kk4 + 2][m] = va.z; As[kk4 + 3][m] = va.w;
            float4 vb = *(const float4*)&W[(size_t)(bn + m) * K + k0 + kk4];
            Bs[kk4 + 0][m] = vb.x; Bs[kk4 + 1][m] = vb.y;
            Bs[kk4 + 2][m] = vb.z; Bs[kk4 + 3][m] = vb.w;
        }
        __syncthreads();
#pragma unroll
        for (int kk = 0; kk < 16; ++kk) {
            float4 a = *(const float4*)&As[kk][tr * 4];
            float4 b = *(const float4*)&Bs[kk][tc * 4];
            float av[4] = {a.x, a.y, a.z, a.w};
            float bv[4] = {b.x, b.y, b.z, b.w};
#pragma unroll
            for (int i = 0; i < 4; ++i)
#pragma unroll
                for (int j = 0; j < 4; ++j) acc[i][j] += av[i] * bv[j];
        }
        __syncthreads();
    }
#pragma unroll
    for (int i = 0; i < 4; ++i) {
        float4 o = make_float4(acc[i][0], acc[i][1], acc[i][2], acc[i][3]);
        *(float4*)&C[(size_t)(bm + tr * 4 + i) * N + bn + tc * 4] = o;
    }
}

// ------------------------------------------------------------------- RoPE ---
__global__ void rope_kernel(float* __restrict__ Qp, float* __restrict__ Kp,
                            const float* __restrict__ cosE, const float* __restrict__ sinE) {
    int idx = blockIdx.x * blockDim.x + threadIdx.x;
    if (idx >= BDIM * SDIM * NHH * 2 * 32) return;
    int i = idx & 31;  idx >>= 5;
    int g = idx & 1;   idx >>= 1;
    int h = idx & 15;  idx >>= 4;
    int s = idx & (SDIM - 1);
    int b = idx >> 11;
    size_t base = ((size_t)(b * SDIM + s)) * HIDD + h * HDD + g * QKDD + 2 * i;
    float c  = cosE[s * HDD + 2 * i];
    float sn = sinE[s * HDD + 2 * i];
    float x0 = Qp[base], x1 = Qp[base + 1];
    Qp[base]     = x0 * c - x1 * sn;
    Qp[base + 1] = x1 * c + x0 * sn;
    x0 = Kp[base]; x1 = Kp[base + 1];
    Kp[base]     = x0 * c - x1 * sn;
    Kp[base + 1] = x1 * c + x0 * sn;
}

// ------------------------------------------------- MFMA differential flash --
// 4 waves/block, 16 q-rows/wave (64 rows/block). KVB=64 keys per tile.
// Scores computed as S^T = K_tile(A) x Q^T(B): D[key][q], col=lane&15=q,
// row=(lane>>4)*4+reg=key. PV: O = P(A) x V(B): D[q][d], row=q, col=d.
#define KVB 64

__device__ __forceinline__ void branch_step(
        f32x4 sc[4], float& M, float& L, f32x4 O[8],
        short* __restrict__ Pl,          // this wave's P buffer, row stride 72
        const short* __restrict__ VTb,   // &VT[0][0], row stride 72
        int t0, int qtop, int lq, int lg) {
    // mask + scale + running max
    float mx = -1e30f;
#pragma unroll
    for (int sub = 0; sub < 4; ++sub)
#pragma unroll
        for (int r = 0; r < 4; ++r) {
            int key = t0 + sub * 16 + lg * 4 + r;
            float s = sc[sub][r] * SCALE_F;
            s = (key <= qtop) ? s : -1e30f;   // qtop = qbase + lq (per-lane q)
            sc[sub][r] = s;
            mx = fmaxf(mx, s);
        }
    mx = fmaxf(mx, __shfl_xor(mx, 16));
    mx = fmaxf(mx, __shfl_xor(mx, 32));
    const float Mn = fmaxf(M, mx);
    const float a = __expf(M - Mn);
    M = Mn;
    float ps = 0.f;
#pragma unroll
    for (int sub = 0; sub < 4; ++sub) {
        float p0 = __expf(sc[sub][0] - Mn);
        float p1 = __expf(sc[sub][1] - Mn);
        float p2 = __expf(sc[sub][2] - Mn);
        float p3 = __expf(sc[sub][3] - Mn);
        ps += (p0 + p1) + (p2 + p3);
        uint2 pw; pw.x = pk2(p0, p1); pw.y = pk2(p2, p3);
        *(uint2*)&Pl[lq * 72 + sub * 16 + lg * 4] = pw;
    }
    ps += __shfl_xor(ps, 16);
    ps += __shfl_xor(ps, 32);
    L = L * a + ps;
    // O rows are q=(lg*4+r): fetch per-row rescale factors
    const float ar0 = __shfl(a, lg * 4 + 0);
    const float ar1 = __shfl(a, lg * 4 + 1);
    const float ar2 = __shfl(a, lg * 4 + 2);
    const float ar3 = __shfl(a, lg * 4 + 3);
#pragma unroll
    for (int d = 0; d < 8; ++d) {
        O[d][0] *= ar0; O[d][1] *= ar1; O[d][2] *= ar2; O[d][3] *= ar3;
    }
    // PV
#pragma unroll
    for (int ks = 0; ks < 2; ++ks) {
        bf16x8 pa = *(const bf16x8*)&Pl[lq * 72 + ks * 32 + lg * 8];
#pragma unroll
        for (int d = 0; d < 8; ++d) {
            bf16x8 vb = *(const bf16x8*)&VTb[(d * 16 + lq) * 72 + ks * 32 + lg * 8];
            O[d] = MFMA16(pa, vb, O[d]);
        }
    }
}

__global__ __launch_bounds__(256, 2) void flash_mfma(
        const float* __restrict__ Qp, const float* __restrict__ Kp,
        const float* __restrict__ Vp, const float* __restrict__ gnw,
        const float* __restrict__ lam_p, float* __restrict__ Hout) {
    __shared__ short Ks[KVB][136];        // row-major K tile (both branches), 272B stride
    __shared__ short VT[HDD][72];         // V^T tile: VT[d][key], 144B stride
    __shared__ short Plds[4][16][72];     // per-wave P, row stride 144B

    const int tid = threadIdx.x;
    const int w  = tid >> 6;
    const int l  = tid & 63;
    const int lq = l & 15;
    const int lg = l >> 4;

    const int blk = blockIdx.x;
    const int bh  = blk & 31;
    const int bx  = 31 - (blk >> 5);      // heavy blocks dispatched first
    const int b = bh >> 4, h = bh & 15;
    const int s0 = bx * 64;
    const float lam = lam_p[0];

    // ---- Q fragments (B operand): col=lq -> q row s0+w*16+lq ----
    const int qg = s0 + w * 16 + lq;
    bf16x8 qf[2][2];
    {
        const float* qrow = Qp + ((size_t)(b * SDIM + qg)) * HIDD + h * HDD;
#pragma unroll
        for (int br = 0; br < 2; ++br)
#pragma unroll
            for (int ks = 0; ks < 2; ++ks) {
                const float* p = qrow + br * 64 + ks * 32 + lg * 8;
                float4 x = *(const float4*)p;
                float4 y = *(const float4*)(p + 4);
                bf16x8 f;
                f[0] = f2bf(x.x); f[1] = f2bf(x.y); f[2] = f2bf(x.z); f[3] = f2bf(x.w);
                f[4] = f2bf(y.x); f[5] = f2bf(y.y); f[6] = f2bf(y.z); f[7] = f2bf(y.w);
                qf[br][ks] = f;
            }
    }
    float gn[8];
#pragma unroll
    for (int d = 0; d < 8; ++d) gn[d] = gnw[d * 16 + lq];

    float M1 = -1e30f, M2 = -1e30f, L1 = 0.f, L2 = 0.f;
    f32x4 O1[8] = {}; f32x4 O2[8] = {};

    const int ntmax = bx + 1;
    const int ntw   = (s0 + w * 16 + 15) / KVB + 1;
    short* Pl = &Plds[w][0][0];

    for (int t = 0; t < ntmax; ++t) {
        const int t0 = t * KVB;
        __syncthreads();
        // ---- stage K (row-major bf16) ----
        {
            const int c4 = (tid & 31) * 4;
            const int k0 = tid >> 5;
#pragma unroll
            for (int i = 0; i < 8; ++i) {
                int key = k0 + i * 8;
                const float* src = Kp + ((size_t)(b * SDIM + t0 + key)) * HIDD + h * HDD + c4;
                float4 v = *(const float4*)src;
                uint2 wv; wv.x = pk2(v.x, v.y); wv.y = pk2(v.z, v.w);
                *(uint2*)&Ks[key][c4] = wv;
            }
        }
        // ---- stage V transposed (VT[d][key]) ----
        {
            const int cidx = tid & 31;
            const int kp2  = tid >> 5;
#pragma unroll
            for (int i = 0; i < 4; ++i) {
                int key0 = kp2 * 2 + i * 16;
                const float* r0 = Vp + ((size_t)(b * SDIM + t0 + key0)) * HIDD + h * HDD;
                const float* r1 = r0 + HIDD;
#pragma unroll
                for (int jj = 0; jj < 4; ++jj) {
                    int c = cidx + jj * 32;
                    *(unsigned*)&VT[c][key0] = pk2(r0[c], r1[c]);
                }
            }
        }
        __syncthreads();
        if (t >= ntw) continue;

        // ---- scores: S^T = K x Q^T, K=64 via 2 mfma, both branches ----
        f32x4 sc1[4] = {{0.f,0.f,0.f,0.f},{0.f,0.f,0.f,0.f},{0.f,0.f,0.f,0.f},{0.f,0.f,0.f,0.f}};
        f32x4 sc2[4] = {{0.f,0.f,0.f,0.f},{0.f,0.f,0.f,0.f},{0.f,0.f,0.f,0.f},{0.f,0.f,0.f,0.f}};
#pragma unroll
        for (int sub = 0; sub < 4; ++sub) {
            const short* krow = &Ks[sub * 16 + lq][0];
            bf16x8 k00 = *(const bf16x8*)(krow + lg * 8);
            bf16x8 k01 = *(const bf16x8*)(krow + 32 + lg * 8);
            bf16x8 k10 = *(const bf16x8*)(krow + 64 + lg * 8);
            bf16x8 k11 = *(const bf16x8*)(krow + 96 + lg * 8);
            sc1[sub] = MFMA16(k00, qf[0][0], sc1[sub]);
            sc1[sub] = MFMA16(k01, qf[0][1], sc1[sub]);
            sc2[sub] = MFMA16(k10, qf[1][0], sc2[sub]);
            sc2[sub] = MFMA16(k11, qf[1][1], sc2[sub]);
        }
        branch_step(sc1, M1, L1, O1, Pl, &VT[0][0], t0, qg, lq, lg);
        branch_step(sc2, M2, L2, O2, Pl, &VT[0][0], t0, qg, lq, lg);
    }

    // ---- epilogue: differential combine + RMSNorm + scales ----
    const float inv1 = 1.f / L1;         // per q=lq
    const float inv2 = lam / L2;
    float i1[4], i2[4];
#pragma unroll
    for (int r = 0; r < 4; ++r) {
        i1[r] = __shfl(inv1, lg * 4 + r);
        i2[r] = __shfl(inv2, lg * 4 + r);
    }
    float od[8][4];
    float ss[4] = {0.f, 0.f, 0.f, 0.f};
#pragma unroll
    for (int d = 0; d < 8; ++d)
#pragma unroll
        for (int r = 0; r < 4; ++r) {
            float o = O1[d][r] * i1[r] - O2[d][r] * i2[r];
            od[d][r] = o;
            ss[r] += o * o;
        }
#pragma unroll
    for (int r = 0; r < 4; ++r) {
        ss[r] += __shfl_xor(ss[r], 1);
        ss[r] += __shfl_xor(ss[r], 2);
        ss[r] += __shfl_xor(ss[r], 4);
        ss[r] += __shfl_xor(ss[r], 8);
    }
#pragma unroll
    for (int r = 0; r < 4; ++r) {
        const float scal = rsqrtf(ss[r] * (1.0f / HDD) + EPS_F) * (1.0f - LAMBDA_INIT_F);
        const size_t orow = ((size_t)(b * SDIM + s0 + w * 16 + lg * 4 + r)) * HIDD + h * HDD;
#pragma unroll
        for (int d = 0; d < 8; ++d)
            Hout[orow + d * 16 + lq] = od[d][r] * scal * gn[d];
    }
}

// ----------------------------------------------------------------- launch ---
extern "C" void kernel_launch(void* const* d_in, const int* in_sizes, int n_in,
                              void* d_out, int out_size, void* d_ws, size_t ws_size,
                              hipStream_t stream) {
    const float* q   = (const float*)d_in[0];
    const float* k   = (const float*)d_in[1];
    const float* v   = (const float*)d_in[2];
    const float* Wq  = (const float*)d_in[3];
    const float* Wk  = (const float*)d_in[4];
    const float* Wv  = (const float*)d_in[5];
    const float* Wo  = (const float*)d_in[6];
    const float* lq1 = (const float*)d_in[7];
    const float* lk1 = (const float*)d_in[8];
    const float* lq2 = (const float*)d_in[9];
    const float* lk2 = (const float*)d_in[10];
    const float* gnw = (const float*)d_in[11];
    const float* cosE = (const float*)d_in[12];
    const float* sinE = (const float*)d_in[13];
    float* out = (float*)d_out;
    float* ws  = (float*)d_ws;

    const size_t TEN = (size_t)BDIM * SDIM * HIDD;
    float* Qp   = ws;
    float* Kp   = ws + TEN;
    float* Vp   = ws + 2 * TEN;
    float* Ho   = ws + 3 * TEN;
    float* lamp = ws + 4 * TEN;

    lambda_kernel<<<1, 64, 0, stream>>>(lq1, lk1, lq2, lk2, lamp);

    dim3 gg(HIDD / 64, MTOT / 64);
    gemm_xwt<<<gg, 256, 0, stream>>>(q, Wq, Qp, MTOT, HIDD, HIDD);
    gemm_xwt<<<gg, 256, 0, stream>>>(k, Wk, Kp, MTOT, HIDD, HIDD);
    gemm_xwt<<<gg, 256, 0, stream>>>(v, Wv, Vp, MTOT, HIDD, HIDD);

    int pairs = BDIM * SDIM * NHH * 2 * (QKDD / 2);
    rope_kernel<<<(pairs + 255) / 256, 256, 0, stream>>>(Qp, Kp, cosE, sinE);

    flash_mfma<<<(SDIM / 64) * BDIM * NHH, 256, 0, stream>>>(Qp, Kp, Vp, gnw, lamp, Ho);

    gemm_xwt<<<gg, 256, 0, stream>>>(Ho, Wo, out, MTOT, HIDD, HIDD);
}

// Round 3
// 626.405 us; speedup vs baseline: 6.8847x; 3.3602x over previous
//
#include <hip/hip_runtime.h>
#include <math.h>

#define BDIM 2
#define SDIM 2048
#define HIDD 2048
#define NHH 16
#define HDD 128
#define QKDD 64
#define MTOT (BDIM*SDIM)   // 4096

constexpr float LAMBDA_INIT_F = 0.3555090675909693f;  // 0.8 - 0.6*exp(-0.3)
constexpr float EPS_F = 1e-6f;
constexpr float SCALE_F = 0.125f;                     // 1/sqrt(64)

typedef float f32x4 __attribute__((ext_vector_type(4)));
typedef short bf16x8 __attribute__((ext_vector_type(8)));

#define MFMA16(a, b, c) __builtin_amdgcn_mfma_f32_16x16x32_bf16((a), (b), (c), 0, 0, 0)

__device__ __forceinline__ short f2bf(float f) {
    unsigned u = __float_as_uint(f);
    u += 0x7FFFu + ((u >> 16) & 1u);   // RNE
    return (short)(u >> 16);
}
__device__ __forceinline__ unsigned pk2(float a, float b) {
    return (unsigned)(unsigned short)f2bf(a) | ((unsigned)(unsigned short)f2bf(b) << 16);
}

__device__ __forceinline__ void gload_lds16(const void* g, void* l) {
    __builtin_amdgcn_global_load_lds(
        (const __attribute__((address_space(1))) void*)g,
        (__attribute__((address_space(3))) void*)l, 16, 0, 0);
}

// ---------------------------------------------------------------- lambda ----
__global__ void lambda_kernel(const float* __restrict__ lq1, const float* __restrict__ lk1,
                              const float* __restrict__ lq2, const float* __restrict__ lk2,
                              float* __restrict__ lam_out) {
    int l = threadIdx.x;
    float d1 = lq1[l] * lk1[l] + lq1[l + 64] * lk1[l + 64];
    float d2 = lq2[l] * lk2[l] + lq2[l + 64] * lk2[l + 64];
#pragma unroll
    for (int o = 32; o > 0; o >>= 1) {
        d1 += __shfl_down(d1, o);
        d2 += __shfl_down(d2, o);
    }
    if (l == 0) lam_out[0] = expf(d1) - expf(d2) + LAMBDA_INIT_F;
}

// ---------------------------------------------------------------- convert ---
__global__ __launch_bounds__(256) void f32_to_bf16(const float* __restrict__ in,
                                                   short* __restrict__ out, int n) {
    int i = (blockIdx.x * 256 + threadIdx.x) * 8;
    if (i >= n) return;
    float4 a = *(const float4*)&in[i];
    float4 b = *(const float4*)&in[i + 4];
    uint4 o;
    o.x = pk2(a.x, a.y); o.y = pk2(a.z, a.w);
    o.z = pk2(b.x, b.y); o.w = pk2(b.z, b.w);
    *(uint4*)&out[i] = o;
}

// ------------------------------------------------------------ bf16 GEMM -----
// C[M,N] fp32 = Ab[M,K] (bf16 row-major) @ Bb[N,K]^T (bf16 row-major).
// m97 structure: 128x128 tile, BK=32, 4 waves (2x2), global_load_lds w=16.
__global__ __launch_bounds__(256) void gemm_bf16(const short* __restrict__ Ab,
                                                 const short* __restrict__ Bb,
                                                 float* __restrict__ C,
                                                 int M, int N, int K) {
    __shared__ short As[128 * 32];
    __shared__ short Bs[128 * 32];
    const int tid = threadIdx.x;
    const int w = tid >> 6, lane = tid & 63;
    const int lq = lane & 15, lg = lane >> 4;
    const int wr = w >> 1, wc = w & 1;
    const int bm = blockIdx.y * 128;
    const int bn = blockIdx.x * 128;

    // staging source: wave w covers tile rows [w*16, w*16+16) and [w*16+64, ...)
    const size_t aoff = (size_t)(bm + w * 16 + (lane >> 2)) * K + (lane & 3) * 8;
    const size_t boff = (size_t)(bn + w * 16 + (lane >> 2)) * K + (lane & 3) * 8;
    const size_t rowskip = (size_t)64 * K;

    f32x4 acc[4][4] = {};

    for (int k0 = 0; k0 < K; k0 += 32) {
        __syncthreads();   // previous tile's readers done
        gload_lds16(Ab + aoff + k0,           &As[w * 512]);
        gload_lds16(Ab + aoff + rowskip + k0, &As[(w + 4) * 512]);
        gload_lds16(Bb + boff + k0,           &Bs[w * 512]);
        gload_lds16(Bb + boff + rowskip + k0, &Bs[(w + 4) * 512]);
        __syncthreads();   // vmcnt(0) drain + barrier: tile visible

        bf16x8 a[4], b[4];
#pragma unroll
        for (int m = 0; m < 4; ++m)
            a[m] = *(const bf16x8*)&As[(wr * 64 + m * 16 + lq) * 32 + lg * 8];
#pragma unroll
        for (int n = 0; n < 4; ++n)
            b[n] = *(const bf16x8*)&Bs[(wc * 64 + n * 16 + lq) * 32 + lg * 8];
#pragma unroll
        for (int m = 0; m < 4; ++m)
#pragma unroll
            for (int n = 0; n < 4; ++n)
                acc[m][n] = MFMA16(a[m], b[n], acc[m][n]);
    }

#pragma unroll
    for (int m = 0; m < 4; ++m)
#pragma unroll
        for (int n = 0; n < 4; ++n) {
            const int row0 = bm + wr * 64 + m * 16 + lg * 4;
            const int col  = bn + wc * 64 + n * 16 + lq;
#pragma unroll
            for (int r = 0; r < 4; ++r)
                C[(size_t)(row0 + r) * N + col] = acc[m][n][r];
        }
}

// ------------------------------------------------------------------- RoPE ---
__global__ void rope_kernel(float* __restrict__ Qp, float* __restrict__ Kp,
                            const float* __restrict__ cosE, const float* __restrict__ sinE) {
    int idx = blockIdx.x * blockDim.x + threadIdx.x;
    if (idx >= BDIM * SDIM * NHH * 2 * 32) return;
    int i = idx & 31;  idx >>= 5;
    int g = idx & 1;   idx >>= 1;
    int h = idx & 15;  idx >>= 4;
    int s = idx & (SDIM - 1);
    int b = idx >> 11;
    size_t base = ((size_t)(b * SDIM + s)) * HIDD + h * HDD + g * QKDD + 2 * i;
    float c  = cosE[s * HDD + 2 * i];
    float sn = sinE[s * HDD + 2 * i];
    float x0 = Qp[base], x1 = Qp[base + 1];
    Qp[base]     = x0 * c - x1 * sn;
    Qp[base + 1] = x1 * c + x0 * sn;
    x0 = Kp[base]; x1 = Kp[base + 1];
    Kp[base]     = x0 * c - x1 * sn;
    Kp[base + 1] = x1 * c + x0 * sn;
}

// ------------------------------------------------- MFMA differential flash --
#define KVB 64

__device__ __forceinline__ void branch_step(
        f32x4 sc[4], float& M, float& L, f32x4 O[8],
        short* __restrict__ Pl,
        const short* __restrict__ VTb,
        int t0, int qtop, int lq, int lg) {
    float mx = -1e30f;
#pragma unroll
    for (int sub = 0; sub < 4; ++sub)
#pragma unroll
        for (int r = 0; r < 4; ++r) {
            int key = t0 + sub * 16 + lg * 4 + r;
            float s = sc[sub][r] * SCALE_F;
            s = (key <= qtop) ? s : -1e30f;
            sc[sub][r] = s;
            mx = fmaxf(mx, s);
        }
    mx = fmaxf(mx, __shfl_xor(mx, 16));
    mx = fmaxf(mx, __shfl_xor(mx, 32));
    const float Mn = fmaxf(M, mx);
    const float a = __expf(M - Mn);
    M = Mn;
    float ps = 0.f;
#pragma unroll
    for (int sub = 0; sub < 4; ++sub) {
        float p0 = __expf(sc[sub][0] - Mn);
        float p1 = __expf(sc[sub][1] - Mn);
        float p2 = __expf(sc[sub][2] - Mn);
        float p3 = __expf(sc[sub][3] - Mn);
        ps += (p0 + p1) + (p2 + p3);
        uint2 pw; pw.x = pk2(p0, p1); pw.y = pk2(p2, p3);
        *(uint2*)&Pl[lq * 72 + sub * 16 + lg * 4] = pw;
    }
    ps += __shfl_xor(ps, 16);
    ps += __shfl_xor(ps, 32);
    L = L * a + ps;
    const float ar0 = __shfl(a, lg * 4 + 0);
    const float ar1 = __shfl(a, lg * 4 + 1);
    const float ar2 = __shfl(a, lg * 4 + 2);
    const float ar3 = __shfl(a, lg * 4 + 3);
#pragma unroll
    for (int d = 0; d < 8; ++d) {
        O[d][0] *= ar0; O[d][1] *= ar1; O[d][2] *= ar2; O[d][3] *= ar3;
    }
#pragma unroll
    for (int ks = 0; ks < 2; ++ks) {
        bf16x8 pa = *(const bf16x8*)&Pl[lq * 72 + ks * 32 + lg * 8];
#pragma unroll
        for (int d = 0; d < 8; ++d) {
            bf16x8 vb = *(const bf16x8*)&VTb[(d * 16 + lq) * 72 + ks * 32 + lg * 8];
            O[d] = MFMA16(pa, vb, O[d]);
        }
    }
}

__global__ __launch_bounds__(256, 2) void flash_mfma(
        const float* __restrict__ Qp, const float* __restrict__ Kp,
        const float* __restrict__ Vp, const float* __restrict__ gnw,
        const float* __restrict__ lam_p, short* __restrict__ Hob) {
    __shared__ short Ks[KVB][136];
    __shared__ short VT[HDD][72];
    __shared__ short Plds[4][16][72];

    const int tid = threadIdx.x;
    const int w  = tid >> 6;
    const int l  = tid & 63;
    const int lq = l & 15;
    const int lg = l >> 4;

    const int blk = blockIdx.x;
    const int bh  = blk & 31;
    const int bx  = 31 - (blk >> 5);
    const int b = bh >> 4, h = bh & 15;
    const int s0 = bx * 64;
    const float lam = lam_p[0];

    const int qg = s0 + w * 16 + lq;
    bf16x8 qf[2][2];
    {
        const float* qrow = Qp + ((size_t)(b * SDIM + qg)) * HIDD + h * HDD;
#pragma unroll
        for (int br = 0; br < 2; ++br)
#pragma unroll
            for (int ks = 0; ks < 2; ++ks) {
                const float* p = qrow + br * 64 + ks * 32 + lg * 8;
                float4 x = *(const float4*)p;
                float4 y = *(const float4*)(p + 4);
                bf16x8 f;
                f[0] = f2bf(x.x); f[1] = f2bf(x.y); f[2] = f2bf(x.z); f[3] = f2bf(x.w);
                f[4] = f2bf(y.x); f[5] = f2bf(y.y); f[6] = f2bf(y.z); f[7] = f2bf(y.w);
                qf[br][ks] = f;
            }
    }
    float gn[8];
#pragma unroll
    for (int d = 0; d < 8; ++d) gn[d] = gnw[d * 16 + lq];

    float M1 = -1e30f, M2 = -1e30f, L1 = 0.f, L2 = 0.f;
    f32x4 O1[8] = {}; f32x4 O2[8] = {};

    const int ntmax = bx + 1;
    const int ntw   = (s0 + w * 16 + 15) / KVB + 1;
    short* Pl = &Plds[w][0][0];

    for (int t = 0; t < ntmax; ++t) {
        const int t0 = t * KVB;
        __syncthreads();
        {
            const int c4 = (tid & 31) * 4;
            const int k0 = tid >> 5;
#pragma unroll
            for (int i = 0; i < 8; ++i) {
                int key = k0 + i * 8;
                const float* src = Kp + ((size_t)(b * SDIM + t0 + key)) * HIDD + h * HDD + c4;
                float4 v = *(const float4*)src;
                uint2 wv; wv.x = pk2(v.x, v.y); wv.y = pk2(v.z, v.w);
                *(uint2*)&Ks[key][c4] = wv;
            }
        }
        {
            const int cidx = tid & 31;
            const int kp2  = tid >> 5;
#pragma unroll
            for (int i = 0; i < 4; ++i) {
                int key0 = kp2 * 2 + i * 16;
                const float* r0 = Vp + ((size_t)(b * SDIM + t0 + key0)) * HIDD + h * HDD;
                const float* r1 = r0 + HIDD;
#pragma unroll
                for (int jj = 0; jj < 4; ++jj) {
                    int c = cidx + jj * 32;
                    *(unsigned*)&VT[c][key0] = pk2(r0[c], r1[c]);
                }
            }
        }
        __syncthreads();
        if (t >= ntw) continue;

        f32x4 sc1[4] = {{0.f,0.f,0.f,0.f},{0.f,0.f,0.f,0.f},{0.f,0.f,0.f,0.f},{0.f,0.f,0.f,0.f}};
        f32x4 sc2[4] = {{0.f,0.f,0.f,0.f},{0.f,0.f,0.f,0.f},{0.f,0.f,0.f,0.f},{0.f,0.f,0.f,0.f}};
#pragma unroll
        for (int sub = 0; sub < 4; ++sub) {
            const short* krow = &Ks[sub * 16 + lq][0];
            bf16x8 k00 = *(const bf16x8*)(krow + lg * 8);
            bf16x8 k01 = *(const bf16x8*)(krow + 32 + lg * 8);
            bf16x8 k10 = *(const bf16x8*)(krow + 64 + lg * 8);
            bf16x8 k11 = *(const bf16x8*)(krow + 96 + lg * 8);
            sc1[sub] = MFMA16(k00, qf[0][0], sc1[sub]);
            sc1[sub] = MFMA16(k01, qf[0][1], sc1[sub]);
            sc2[sub] = MFMA16(k10, qf[1][0], sc2[sub]);
            sc2[sub] = MFMA16(k11, qf[1][1], sc2[sub]);
        }
        branch_step(sc1, M1, L1, O1, Pl, &VT[0][0], t0, qg, lq, lg);
        branch_step(sc2, M2, L2, O2, Pl, &VT[0][0], t0, qg, lq, lg);
    }

    const float inv1 = 1.f / L1;
    const float inv2 = lam / L2;
    float i1[4], i2[4];
#pragma unroll
    for (int r = 0; r < 4; ++r) {
        i1[r] = __shfl(inv1, lg * 4 + r);
        i2[r] = __shfl(inv2, lg * 4 + r);
    }
    float od[8][4];
    float ss[4] = {0.f, 0.f, 0.f, 0.f};
#pragma unroll
    for (int d = 0; d < 8; ++d)
#pragma unroll
        for (int r = 0; r < 4; ++r) {
            float o = O1[d][r] * i1[r] - O2[d][r] * i2[r];
            od[d][r] = o;
            ss[r] += o * o;
        }
#pragma unroll
    for (int r = 0; r < 4; ++r) {
        ss[r] += __shfl_xor(ss[r], 1);
        ss[r] += __shfl_xor(ss[r], 2);
        ss[r] += __shfl_xor(ss[r], 4);
        ss[r] += __shfl_xor(ss[r], 8);
    }
#pragma unroll
    for (int r = 0; r < 4; ++r) {
        const float scal = rsqrtf(ss[r] * (1.0f / HDD) + EPS_F) * (1.0f - LAMBDA_INIT_F);
        const size_t orow = ((size_t)(b * SDIM + s0 + w * 16 + lg * 4 + r)) * HIDD + h * HDD;
#pragma unroll
        for (int d = 0; d < 8; ++d)
            Hob[orow + d * 16 + lq] = f2bf(od[d][r] * scal * gn[d]);
    }
}

// ----------------------------------------------------------------- launch ---
extern "C" void kernel_launch(void* const* d_in, const int* in_sizes, int n_in,
                              void* d_out, int out_size, void* d_ws, size_t ws_size,
                              hipStream_t stream) {
    const float* q   = (const float*)d_in[0];
    const float* k   = (const float*)d_in[1];
    const float* v   = (const float*)d_in[2];
    const float* Wq  = (const float*)d_in[3];
    const float* Wk  = (const float*)d_in[4];
    const float* Wv  = (const float*)d_in[5];
    const float* Wo  = (const float*)d_in[6];
    const float* lq1 = (const float*)d_in[7];
    const float* lk1 = (const float*)d_in[8];
    const float* lq2 = (const float*)d_in[9];
    const float* lk2 = (const float*)d_in[10];
    const float* gnw = (const float*)d_in[11];
    const float* cosE = (const float*)d_in[12];
    const float* sinE = (const float*)d_in[13];
    float* out = (float*)d_out;
    float* ws  = (float*)d_ws;

    const size_t TEN = (size_t)BDIM * SDIM * HIDD;  // 8388608 elements (X)
    const int   WN  = HIDD * HIDD;                  // 4194304 elements (W)

    float* Qp   = ws;
    float* Kp   = ws + TEN;
    float* Vp   = ws + 2 * TEN;
    short* xb   = (short*)(ws + 3 * TEN);           // TEN shorts; reused as Hob
    short* wb   = (short*)(ws + 3 * TEN + TEN / 2); // WN shorts
    float* lamp = ws + 3 * TEN + TEN / 2 + TEN / 4;

    lambda_kernel<<<1, 64, 0, stream>>>(lq1, lk1, lq2, lk2, lamp);

    const int cgX = (int)(TEN / 8 / 256);   // 4096 blocks
    const int cgW = WN / 8 / 256;           // 2048 blocks
    dim3 gg(HIDD / 128, MTOT / 128);        // 16 x 32

    f32_to_bf16<<<cgX, 256, 0, stream>>>(q, xb, (int)TEN);
    f32_to_bf16<<<cgW, 256, 0, stream>>>(Wq, wb, WN);
    gemm_bf16<<<gg, 256, 0, stream>>>(xb, wb, Qp, MTOT, HIDD, HIDD);

    f32_to_bf16<<<cgX, 256, 0, stream>>>(k, xb, (int)TEN);
    f32_to_bf16<<<cgW, 256, 0, stream>>>(Wk, wb, WN);
    gemm_bf16<<<gg, 256, 0, stream>>>(xb, wb, Kp, MTOT, HIDD, HIDD);

    f32_to_bf16<<<cgX, 256, 0, stream>>>(v, xb, (int)TEN);
    f32_to_bf16<<<cgW, 256, 0, stream>>>(Wv, wb, WN);
    gemm_bf16<<<gg, 256, 0, stream>>>(xb, wb, Vp, MTOT, HIDD, HIDD);

    int pairs = BDIM * SDIM * NHH * 2 * (QKDD / 2);
    rope_kernel<<<(pairs + 255) / 256, 256, 0, stream>>>(Qp, Kp, cosE, sinE);

    flash_mfma<<<(SDIM / 64) * BDIM * NHH, 256, 0, stream>>>(Qp, Kp, Vp, gnw, lamp, xb);

    f32_to_bf16<<<cgW, 256, 0, stream>>>(Wo, wb, WN);
    gemm_bf16<<<gg, 256, 0, stream>>>(xb, wb, out, MTOT, HIDD, HIDD);
}

// Round 5
// 374.556 us; speedup vs baseline: 11.5139x; 1.6724x over previous
//
#include <hip/hip_runtime.h>
#include <math.h>

#define BDIM 2
#define SDIM 2048
#define HIDD 2048
#define NHH 16
#define HDD 128
#define QKDD 64
#define MTOT (BDIM*SDIM)   // 4096

constexpr float LAMBDA_INIT_F = 0.3555090675909693f;  // 0.8 - 0.6*exp(-0.3)
constexpr float EPS_F = 1e-6f;
constexpr float SCALE_F = 0.125f;                     // 1/sqrt(64)

typedef float f32x4 __attribute__((ext_vector_type(4)));
typedef short bf16x8 __attribute__((ext_vector_type(8)));
typedef short bf16x4 __attribute__((ext_vector_type(4)));

#define MFMA16(a, b, c) __builtin_amdgcn_mfma_f32_16x16x32_bf16((a), (b), (c), 0, 0, 0)

__device__ __forceinline__ short f2bf(float f) {
    unsigned u = __float_as_uint(f);
    u += 0x7FFFu + ((u >> 16) & 1u);   // RNE
    return (short)(u >> 16);
}
__device__ __forceinline__ unsigned pk2(float a, float b) {
    return (unsigned)(unsigned short)f2bf(a) | ((unsigned)(unsigned short)f2bf(b) << 16);
}

__device__ __forceinline__ void gload_lds16(const void* g, void* l) {
    __builtin_amdgcn_global_load_lds(
        (const __attribute__((address_space(1))) void*)g,
        (__attribute__((address_space(3))) void*)l, 16, 0, 0);
}

// ---------------------------------------------------------------- lambda ----
__global__ void lambda_kernel(const float* __restrict__ lq1, const float* __restrict__ lk1,
                              const float* __restrict__ lq2, const float* __restrict__ lk2,
                              float* __restrict__ lam_out) {
    int l = threadIdx.x;
    float d1 = lq1[l] * lk1[l] + lq1[l + 64] * lk1[l + 64];
    float d2 = lq2[l] * lk2[l] + lq2[l + 64] * lk2[l + 64];
#pragma unroll
    for (int o = 32; o > 0; o >>= 1) {
        d1 += __shfl_down(d1, o);
        d2 += __shfl_down(d2, o);
    }
    if (l == 0) lam_out[0] = expf(d1) - expf(d2) + LAMBDA_INIT_F;
}

// ---------------------------------------------------------------- convert ---
__global__ __launch_bounds__(256) void f32_to_bf16(const float* __restrict__ in,
                                                   short* __restrict__ out, int n) {
    int i = (blockIdx.x * 256 + threadIdx.x) * 8;
    if (i >= n) return;
    float4 a = *(const float4*)&in[i];
    float4 b = *(const float4*)&in[i + 4];
    uint4 o;
    o.x = pk2(a.x, a.y); o.y = pk2(a.z, a.w);
    o.z = pk2(b.x, b.y); o.w = pk2(b.z, b.w);
    *(uint4*)&out[i] = o;
}

// ------------------------------------------------------------ bf16 GEMM -----
// C[M,N] = Ab[M,K] (bf16) @ Bb[N,K]^T (bf16).
// MODE 0: fp32 C.  MODE 1: bf16 C.  MODE 2: bf16 C with fused RoPE epilogue.
template<int MODE>
__global__ __launch_bounds__(256) void gemm_bf16(const short* __restrict__ Ab,
                                                 const short* __restrict__ Bb,
                                                 void* __restrict__ Cv,
                                                 const float* __restrict__ cosE,
                                                 const float* __restrict__ sinE,
                                                 int M, int N, int K) {
    __shared__ short As[128 * 32];
    __shared__ short Bs[128 * 32];
    const int tid = threadIdx.x;
    const int w = tid >> 6, lane = tid & 63;
    const int lq = lane & 15, lg = lane >> 4;
    const int wr = w >> 1, wc = w & 1;
    const int bm = blockIdx.y * 128;
    const int bn = blockIdx.x * 128;

    const size_t aoff = (size_t)(bm + w * 16 + (lane >> 2)) * K + (lane & 3) * 8;
    const size_t boff = (size_t)(bn + w * 16 + (lane >> 2)) * K + (lane & 3) * 8;
    const size_t rowskip = (size_t)64 * K;

    f32x4 acc[4][4] = {};

    for (int k0 = 0; k0 < K; k0 += 32) {
        __syncthreads();
        gload_lds16(Ab + aoff + k0,           &As[w * 512]);
        gload_lds16(Ab + aoff + rowskip + k0, &As[(w + 4) * 512]);
        gload_lds16(Bb + boff + k0,           &Bs[w * 512]);
        gload_lds16(Bb + boff + rowskip + k0, &Bs[(w + 4) * 512]);
        __syncthreads();

        bf16x8 a[4], b[4];
#pragma unroll
        for (int m = 0; m < 4; ++m)
            a[m] = *(const bf16x8*)&As[(wr * 64 + m * 16 + lq) * 32 + lg * 8];
#pragma unroll
        for (int n = 0; n < 4; ++n)
            b[n] = *(const bf16x8*)&Bs[(wc * 64 + n * 16 + lq) * 32 + lg * 8];
#pragma unroll
        for (int m = 0; m < 4; ++m)
#pragma unroll
            for (int n = 0; n < 4; ++n)
                acc[m][n] = MFMA16(a[m], b[n], acc[m][n]);
    }

    if constexpr (MODE == 0) {
        float* C = (float*)Cv;
#pragma unroll
        for (int m = 0; m < 4; ++m)
#pragma unroll
            for (int n = 0; n < 4; ++n) {
                const int row0 = bm + wr * 64 + m * 16 + lg * 4;
                const int col  = bn + wc * 64 + n * 16 + lq;
#pragma unroll
                for (int r = 0; r < 4; ++r)
                    C[(size_t)(row0 + r) * N + col] = acc[m][n][r];
            }
    } else {
        short* Cb = (short*)Cv;
#pragma unroll
        for (int m = 0; m < 4; ++m)
#pragma unroll
            for (int n = 0; n < 4; ++n) {
                const int row0 = bm + wr * 64 + m * 16 + lg * 4;
                const int col  = bn + wc * 64 + n * 16 + lq;
#pragma unroll
                for (int r = 0; r < 4; ++r) {
                    float vv = acc[m][n][r];
                    if constexpr (MODE == 2) {
                        const int s  = (row0 + r) & (SDIM - 1);
                        const int c6 = col & 63;
                        const float cv = cosE[s * HDD + c6];
                        const float sv = sinE[s * HDD + c6];
                        const float p = __shfl_xor(vv, 1);
                        vv = (col & 1) ? vv * cv + p * sv : vv * cv - p * sv;
                    }
                    Cb[(size_t)(row0 + r) * N + col] = f2bf(vv);
                }
            }
    }
}

// ------------------------------------------------- MFMA differential flash --
// 4 waves x 16 q-rows. KVB=64. Scores: S^T = K(A) x Q^T(B): lane (lq=q, lg),
// sc[sub][r] = S[key=sub*16+lg*4+r][q=lq]. P never touches LDS: packed P keys
// at MFMA k-slot s=lg*8+e are key pi(s)=(e>>2)*16+lg*4+(e&3); V is read from
// VT[d][key] in the SAME permuted key order -> contraction unchanged.
#define KVB 64

__device__ __forceinline__ bf16x8 pack_pa(const float p0[4], const float p1[4]) {
    union { unsigned u[4]; bf16x8 v; } r;
    r.u[0] = pk2(p0[0], p0[1]);
    r.u[1] = pk2(p0[2], p0[3]);
    r.u[2] = pk2(p1[0], p1[1]);
    r.u[3] = pk2(p1[2], p1[3]);
    return r.v;
}

__device__ __forceinline__ void softmax_step(
        f32x4 sc[4], float& M, float& L, f32x4 O[8], bf16x8 pa[2],
        int t0, int qg, int lg, bool domask) {
#pragma unroll
    for (int sub = 0; sub < 4; ++sub)
#pragma unroll
        for (int r = 0; r < 4; ++r) {
            float s = sc[sub][r] * SCALE_F;
            if (domask) {
                int key = t0 + sub * 16 + lg * 4 + r;
                s = (key <= qg) ? s : -1e30f;
            }
            sc[sub][r] = s;
        }
    float mx = -1e30f;
#pragma unroll
    for (int sub = 0; sub < 4; ++sub) {
        float a01 = fmaxf(sc[sub][0], sc[sub][1]);
        float a23 = fmaxf(sc[sub][2], sc[sub][3]);
        mx = fmaxf(mx, fmaxf(a01, a23));
    }
    mx = fmaxf(mx, __shfl_xor(mx, 16));
    mx = fmaxf(mx, __shfl_xor(mx, 32));
    if (__ballot(mx > M + 8.f)) {           // defer-max (T13, THR=8)
        const float Mn = fmaxf(M, mx);
        const float a = __expf(M - Mn);
        M = Mn;
        L *= a;
        float ar[4];
#pragma unroll
        for (int r = 0; r < 4; ++r) ar[r] = __shfl(a, lg * 4 + r);
#pragma unroll
        for (int d = 0; d < 8; ++d) {
            O[d][0] *= ar[0]; O[d][1] *= ar[1]; O[d][2] *= ar[2]; O[d][3] *= ar[3];
        }
    }
    float p[4][4];
    float ps = 0.f;
#pragma unroll
    for (int sub = 0; sub < 4; ++sub) {
#pragma unroll
        for (int r = 0; r < 4; ++r) p[sub][r] = __expf(sc[sub][r] - M);
        ps += (p[sub][0] + p[sub][1]) + (p[sub][2] + p[sub][3]);
    }
    ps += __shfl_xor(ps, 16);
    ps += __shfl_xor(ps, 32);
    L += ps;
    pa[0] = pack_pa(p[0], p[1]);   // keys {lg*4+0..3, 16+lg*4+0..3}
    pa[1] = pack_pa(p[2], p[3]);   // keys {32+lg*4+0..3, 48+lg*4+0..3}
}

__global__ __launch_bounds__(256, 2) void flash_mfma(
        const short* __restrict__ Qb, const short* __restrict__ Kb,
        const short* __restrict__ Vb, const float* __restrict__ gnw,
        const float* __restrict__ lam_p, short* __restrict__ Hob) {
    __shared__ short Ksh[KVB * 128];   // row-major, 16B-group xor-swizzled
    __shared__ short VT[HDD * 72];     // VT[d][key], row stride 72 shorts

    const int tid = threadIdx.x;
    const int w  = tid >> 6;
    const int l  = tid & 63;
    const int lq = l & 15;
    const int lg = l >> 4;

    const int blk = blockIdx.x;
    const int bh  = blk & 31;
    const int bx  = 31 - (blk >> 5);      // heavy blocks first
    const int b = bh >> 4, h = bh & 15;
    const int s0 = bx * 64;
    const float lam = lam_p[0];

    // Q fragments (B operand): col=lq -> q row s0+w*16+lq
    const int qg = s0 + w * 16 + lq;
    const short* qrow = Qb + ((size_t)(b * SDIM + qg)) * HIDD + h * HDD;
    bf16x8 qf[2][2];
#pragma unroll
    for (int br = 0; br < 2; ++br)
#pragma unroll
        for (int ks = 0; ks < 2; ++ks)
            qf[br][ks] = *(const bf16x8*)(qrow + br * 64 + ks * 32 + lg * 8);

    // K staging: linear LDS dest, swizzle folded into global source column
    int kkey[4], kcol[4];
#pragma unroll
    for (int i = 0; i < 4; ++i) {
        kkey[i] = w * 16 + i * 4 + lg;
        kcol[i] = (lq * 8) ^ ((kkey[i] & 7) << 3);
    }
    // V staging: thread owns keys {2kp, 2kp+1} x d-range [dq*16, dq*16+16)
    const int kp = tid & 31, dq = tid >> 5;

    const short* Kbase = Kb + ((size_t)(b * SDIM)) * HIDD + h * HDD;
    const short* Vbase = Vb + ((size_t)(b * SDIM)) * HIDD + h * HDD;

    float M1 = -1e30f, M2 = -1e30f, L1 = 0.f, L2 = 0.f;
    f32x4 O1[8] = {}; f32x4 O2[8] = {};

    const int ntmax = bx + 1;
    const int qmin = s0 + w * 16;
    const int ntw = (qmin >> 6) + 1;

    for (int t = 0; t < ntmax; ++t) {
        const size_t trow = (size_t)t * KVB * HIDD;
        __syncthreads();   // previous tile's readers done
#pragma unroll
        for (int i = 0; i < 4; ++i)
            gload_lds16(Kbase + trow + (size_t)kkey[i] * HIDD + kcol[i],
                        &Ksh[w * 2048 + i * 512]);
        {
            const short* v0 = Vbase + trow + (size_t)(2 * kp) * HIDD + dq * 16;
            const short* v1 = v0 + HIDD;
            bf16x8 v00 = *(const bf16x8*)v0;
            bf16x8 v01 = *(const bf16x8*)(v0 + 8);
            bf16x8 v10 = *(const bf16x8*)v1;
            bf16x8 v11 = *(const bf16x8*)(v1 + 8);
#pragma unroll
            for (int j = 0; j < 8; ++j) {
                unsigned ua = (unsigned)(unsigned short)v00[j] |
                              ((unsigned)(unsigned short)v10[j] << 16);
                *(unsigned*)&VT[(dq * 16 + j) * 72 + 2 * kp] = ua;
                unsigned ub = (unsigned)(unsigned short)v01[j] |
                              ((unsigned)(unsigned short)v11[j] << 16);
                *(unsigned*)&VT[(dq * 16 + 8 + j) * 72 + 2 * kp] = ub;
            }
        }
        __syncthreads();   // tile visible
        if (t >= ntw) continue;

        // ---- scores, both branches ----
        f32x4 sc1[4] = {}; f32x4 sc2[4] = {};
        const int rsw = (lq & 7) << 3;
#pragma unroll
        for (int sub = 0; sub < 4; ++sub) {
            const int rbase = (sub * 16 + lq) * 128;
            bf16x8 k00 = *(const bf16x8*)&Ksh[rbase + ((lg * 8) ^ rsw)];
            bf16x8 k01 = *(const bf16x8*)&Ksh[rbase + ((32 + lg * 8) ^ rsw)];
            bf16x8 k10 = *(const bf16x8*)&Ksh[rbase + ((64 + lg * 8) ^ rsw)];
            bf16x8 k11 = *(const bf16x8*)&Ksh[rbase + ((96 + lg * 8) ^ rsw)];
            sc1[sub] = MFMA16(k00, qf[0][0], sc1[sub]);
            sc1[sub] = MFMA16(k01, qf[0][1], sc1[sub]);
            sc2[sub] = MFMA16(k10, qf[1][0], sc2[sub]);
            sc2[sub] = MFMA16(k11, qf[1][1], sc2[sub]);
        }
        const int t0 = t * KVB;
        const bool domask = (t0 + KVB - 1 > qmin);
        bf16x8 pa1[2], pa2[2];
        softmax_step(sc1, M1, L1, O1, pa1, t0, qg, lg, domask);
        softmax_step(sc2, M2, L2, O2, pa2, t0, qg, lg, domask);

        // ---- PV: V read in the SAME key permutation as packed P ----
#pragma unroll
        for (int d0 = 0; d0 < 8; ++d0) {
            const short* vrow = &VT[(d0 * 16 + lq) * 72];
            bf16x4 a0 = *(const bf16x4*)&vrow[lg * 4];        // keys lg*4+0..3
            bf16x4 a1 = *(const bf16x4*)&vrow[16 + lg * 4];   // keys 16+lg*4+0..3
            bf16x4 b0 = *(const bf16x4*)&vrow[32 + lg * 4];
            bf16x4 b1 = *(const bf16x4*)&vrow[48 + lg * 4];
            bf16x8 vb0 = __builtin_shufflevector(a0, a1, 0, 1, 2, 3, 4, 5, 6, 7);
            bf16x8 vb1 = __builtin_shufflevector(b0, b1, 0, 1, 2, 3, 4, 5, 6, 7);
            O1[d0] = MFMA16(pa1[0], vb0, O1[d0]);
            O1[d0] = MFMA16(pa1[1], vb1, O1[d0]);
            O2[d0] = MFMA16(pa2[0], vb0, O2[d0]);
            O2[d0] = MFMA16(pa2[1], vb1, O2[d0]);
        }
    }

    // ---- epilogue: differential combine + RMSNorm + scales ----
    const float inv1 = 1.f / L1;
    const float inv2 = lam / L2;
    float i1[4], i2[4];
#pragma unroll
    for (int r = 0; r < 4; ++r) {
        i1[r] = __shfl(inv1, lg * 4 + r);
        i2[r] = __shfl(inv2, lg * 4 + r);
    }
    float gn[8];
#pragma unroll
    for (int d = 0; d < 8; ++d) gn[d] = gnw[d * 16 + lq];
    float od[8][4];
    float ss[4] = {0.f, 0.f, 0.f, 0.f};
#pragma unroll
    for (int d = 0; d < 8; ++d)
#pragma unroll
        for (int r = 0; r < 4; ++r) {
            float o = O1[d][r] * i1[r] - O2[d][r] * i2[r];
            od[d][r] = o;
            ss[r] += o * o;
        }
#pragma unroll
    for (int r = 0; r < 4; ++r) {
        ss[r] += __shfl_xor(ss[r], 1);
        ss[r] += __shfl_xor(ss[r], 2);
        ss[r] += __shfl_xor(ss[r], 4);
        ss[r] += __shfl_xor(ss[r], 8);
    }
#pragma unroll
    for (int r = 0; r < 4; ++r) {
        const float scal = rsqrtf(ss[r] * (1.0f / HDD) + EPS_F) * (1.0f - LAMBDA_INIT_F);
        const size_t orow = ((size_t)(b * SDIM + s0 + w * 16 + lg * 4 + r)) * HIDD + h * HDD;
#pragma unroll
        for (int d = 0; d < 8; ++d)
            Hob[orow + d * 16 + lq] = f2bf(od[d][r] * scal * gn[d]);
    }
}

// ----------------------------------------------------------------- launch ---
extern "C" void kernel_launch(void* const* d_in, const int* in_sizes, int n_in,
                              void* d_out, int out_size, void* d_ws, size_t ws_size,
                              hipStream_t stream) {
    const float* q   = (const float*)d_in[0];
    const float* k   = (const float*)d_in[1];
    const float* v   = (const float*)d_in[2];
    const float* Wq  = (const float*)d_in[3];
    const float* Wk  = (const float*)d_in[4];
    const float* Wv  = (const float*)d_in[5];
    const float* Wo  = (const float*)d_in[6];
    const float* lq1 = (const float*)d_in[7];
    const float* lk1 = (const float*)d_in[8];
    const float* lq2 = (const float*)d_in[9];
    const float* lk2 = (const float*)d_in[10];
    const float* gnw = (const float*)d_in[11];
    const float* cosE = (const float*)d_in[12];
    const float* sinE = (const float*)d_in[13];
    float* out = (float*)d_out;

    const size_t TEN = (size_t)BDIM * SDIM * HIDD;  // 8388608
    const int   WN  = HIDD * HIDD;                  // 4194304

    short* wsS = (short*)d_ws;
    short* Qb   = wsS;
    short* Kb   = wsS + TEN;
    short* Vb   = wsS + 2 * TEN;
    short* xb   = wsS + 3 * TEN;                    // X bf16; reused as Hob
    short* wb   = wsS + 4 * TEN;
    float* lamp = (float*)(wsS + 4 * TEN + WN);

    lambda_kernel<<<1, 64, 0, stream>>>(lq1, lk1, lq2, lk2, lamp);

    const int cgX = (int)(TEN / 8 / 256);
    const int cgW = WN / 8 / 256;
    dim3 gg(HIDD / 128, MTOT / 128);

    f32_to_bf16<<<cgX, 256, 0, stream>>>(q, xb, (int)TEN);
    f32_to_bf16<<<cgW, 256, 0, stream>>>(Wq, wb, WN);
    gemm_bf16<2><<<gg, 256, 0, stream>>>(xb, wb, Qb, cosE, sinE, MTOT, HIDD, HIDD);

    f32_to_bf16<<<cgX, 256, 0, stream>>>(k, xb, (int)TEN);
    f32_to_bf16<<<cgW, 256, 0, stream>>>(Wk, wb, WN);
    gemm_bf16<2><<<gg, 256, 0, stream>>>(xb, wb, Kb, cosE, sinE, MTOT, HIDD, HIDD);

    f32_to_bf16<<<cgX, 256, 0, stream>>>(v, xb, (int)TEN);
    f32_to_bf16<<<cgW, 256, 0, stream>>>(Wv, wb, WN);
    gemm_bf16<1><<<gg, 256, 0, stream>>>(xb, wb, Vb, nullptr, nullptr, MTOT, HIDD, HIDD);

    flash_mfma<<<(SDIM / 64) * BDIM * NHH, 256, 0, stream>>>(Qb, Kb, Vb, gnw, lamp, xb);

    f32_to_bf16<<<cgW, 256, 0, stream>>>(Wo, wb, WN);
    gemm_bf16<0><<<gg, 256, 0, stream>>>(xb, wb, out, nullptr, nullptr, MTOT, HIDD, HIDD);
}

// Round 6
// 330.592 us; speedup vs baseline: 13.0451x; 1.1330x over previous
//
#include <hip/hip_runtime.h>
#include <math.h>

#define BDIM 2
#define SDIM 2048
#define HIDD 2048
#define NHH 16
#define HDD 128
#define QKDD 64
#define MTOT (BDIM*SDIM)   // 4096

constexpr float LAMBDA_INIT_F = 0.3555090675909693f;  // 0.8 - 0.6*exp(-0.3)
constexpr float EPS_F = 1e-6f;
constexpr float SCALE_F = 0.125f;                     // 1/sqrt(64)

typedef float f32x4 __attribute__((ext_vector_type(4)));
typedef short bf16x8 __attribute__((ext_vector_type(8)));
typedef short bf16x4 __attribute__((ext_vector_type(4)));

#define MFMA16(a, b, c) __builtin_amdgcn_mfma_f32_16x16x32_bf16((a), (b), (c), 0, 0, 0)

__device__ __forceinline__ short f2bf(float f) {
    unsigned u = __float_as_uint(f);
    u += 0x7FFFu + ((u >> 16) & 1u);   // RNE
    return (short)(u >> 16);
}
__device__ __forceinline__ unsigned pk2(float a, float b) {
    return (unsigned)(unsigned short)f2bf(a) | ((unsigned)(unsigned short)f2bf(b) << 16);
}

__device__ __forceinline__ void gload_lds16(const void* g, void* l) {
    __builtin_amdgcn_global_load_lds(
        (const __attribute__((address_space(1))) void*)g,
        (__attribute__((address_space(3))) void*)l, 16, 0, 0);
}

// ---------------------------------------------------------------- lambda ----
__global__ void lambda_kernel(const float* __restrict__ lq1, const float* __restrict__ lk1,
                              const float* __restrict__ lq2, const float* __restrict__ lk2,
                              float* __restrict__ lam_out) {
    int l = threadIdx.x;
    float d1 = lq1[l] * lk1[l] + lq1[l + 64] * lk1[l + 64];
    float d2 = lq2[l] * lk2[l] + lq2[l + 64] * lk2[l + 64];
#pragma unroll
    for (int o = 32; o > 0; o >>= 1) {
        d1 += __shfl_down(d1, o);
        d2 += __shfl_down(d2, o);
    }
    if (l == 0) lam_out[0] = expf(d1) - expf(d2) + LAMBDA_INIT_F;
}

// ---------------------------------------------------------------- convert ---
// Batched: blockIdx.y selects the tensor.
__global__ __launch_bounds__(256) void conv_x(const float* __restrict__ s0,
                                              const float* __restrict__ s1,
                                              const float* __restrict__ s2,
                                              short* __restrict__ dst, int n) {
    const float* src = (blockIdx.y == 0) ? s0 : (blockIdx.y == 1) ? s1 : s2;
    short* out = dst + (size_t)blockIdx.y * n;
    int i = (blockIdx.x * 256 + threadIdx.x) * 8;
    if (i >= n) return;
    float4 a = *(const float4*)&src[i];
    float4 b = *(const float4*)&src[i + 4];
    uint4 o;
    o.x = pk2(a.x, a.y); o.y = pk2(a.z, a.w);
    o.z = pk2(b.x, b.y); o.w = pk2(b.z, b.w);
    *(uint4*)&out[i] = o;
}
__global__ __launch_bounds__(256) void conv_w(const float* __restrict__ s0,
                                              const float* __restrict__ s1,
                                              const float* __restrict__ s2,
                                              const float* __restrict__ s3,
                                              short* __restrict__ dst, int n) {
    const float* src = (blockIdx.y == 0) ? s0 : (blockIdx.y == 1) ? s1
                     : (blockIdx.y == 2) ? s2 : s3;
    short* out = dst + (size_t)blockIdx.y * n;
    int i = (blockIdx.x * 256 + threadIdx.x) * 8;
    if (i >= n) return;
    float4 a = *(const float4*)&src[i];
    float4 b = *(const float4*)&src[i + 4];
    uint4 o;
    o.x = pk2(a.x, a.y); o.y = pk2(a.z, a.w);
    o.z = pk2(b.x, b.y); o.w = pk2(b.z, b.w);
    *(uint4*)&out[i] = o;
}

// ------------------------------------------------------------ bf16 GEMM -----
// Shared mainloop: C[M,N] = X[M,K](bf16) @ W[N,K]^T(bf16). 128x128 tile,
// BK=64, 4 waves (2x2). LDS XOR-swizzled in 16B units (inverse folded into
// the global_load_lds source column; read-side XOR is (lq&7)<<3, constant).
#define GK 2048

__device__ __forceinline__ void gemm_mainloop(
        const short* __restrict__ X, const short* __restrict__ W,
        short* As, short* Bs, f32x4 acc[4][4],
        int bm, int bn, int w, int l, int lq, int lg, int wr, int wc) {
    const int scol = (((l & 7) ^ (l >> 3)) << 3);
    const int rsw  = (lq & 7) << 3;
    const short* aS[4]; const short* bS[4];
    short* aD[4]; short* bD[4];
#pragma unroll
    for (int i = 0; i < 4; ++i) {
        const int c = w * 4 + i;
        aS[i] = X + (size_t)(bm + c * 8 + (l >> 3)) * GK + scol;
        bS[i] = W + (size_t)(bn + c * 8 + (l >> 3)) * GK + scol;
        aD[i] = As + c * 512;
        bD[i] = Bs + c * 512;
    }
    for (int k0 = 0; k0 < GK; k0 += 64) {
        __syncthreads();
#pragma unroll
        for (int i = 0; i < 4; ++i) {
            gload_lds16(aS[i] + k0, aD[i]);
            gload_lds16(bS[i] + k0, bD[i]);
        }
        __syncthreads();
#pragma unroll
        for (int kk = 0; kk < 2; ++kk) {
            bf16x8 a[4], b[4];
#pragma unroll
            for (int m = 0; m < 4; ++m)
                a[m] = *(const bf16x8*)&As[(wr * 64 + m * 16 + lq) * 64 + ((kk * 32 + lg * 8) ^ rsw)];
#pragma unroll
            for (int n = 0; n < 4; ++n)
                b[n] = *(const bf16x8*)&Bs[(wc * 64 + n * 16 + lq) * 64 + ((kk * 32 + lg * 8) ^ rsw)];
#pragma unroll
            for (int m = 0; m < 4; ++m)
#pragma unroll
                for (int n = 0; n < 4; ++n)
                    acc[m][n] = MFMA16(a[m], b[n], acc[m][n]);
        }
    }
}

// Batched QKV projection: z=0 -> Q (RoPE), z=1 -> K (RoPE), z=2 -> V (plain).
__global__ __launch_bounds__(256) void qkv_gemm(
        const short* __restrict__ Xq, const short* __restrict__ Xk, const short* __restrict__ Xv,
        const short* __restrict__ Wb, short* __restrict__ Qb, short* __restrict__ Kb,
        short* __restrict__ Vb, const float* __restrict__ cosE, const float* __restrict__ sinE) {
    __shared__ short As[128 * 64];
    __shared__ short Bs[128 * 64];
    const int tid = threadIdx.x;
    const int w = tid >> 6, l = tid & 63;
    const int lq = l & 15, lg = l >> 4;
    const int wr = w >> 1, wc = w & 1;
    const int bm = blockIdx.y * 128;
    const int bn = blockIdx.x * 128;
    const int z  = blockIdx.z;

    const short* X = (z == 0) ? Xq : (z == 1) ? Xk : Xv;
    const short* W = Wb + (size_t)z * HIDD * HIDD;
    short* Cb      = (z == 0) ? Qb : (z == 1) ? Kb : Vb;

    f32x4 acc[4][4] = {};
    gemm_mainloop(X, W, As, Bs, acc, bm, bn, w, l, lq, lg, wr, wc);

    const bool dorope = (z < 2);
#pragma unroll
    for (int m = 0; m < 4; ++m)
#pragma unroll
        for (int n = 0; n < 4; ++n) {
            const int row0 = bm + wr * 64 + m * 16 + lg * 4;
            const int col  = bn + wc * 64 + n * 16 + lq;
#pragma unroll
            for (int r = 0; r < 4; ++r) {
                float vv = acc[m][n][r];
                if (dorope) {
                    const int s  = (row0 + r) & (SDIM - 1);
                    const int c6 = col & 63;
                    const float cv = cosE[s * HDD + c6];
                    const float sv = sinE[s * HDD + c6];
                    const float p = __shfl_xor(vv, 1);
                    vv = (col & 1) ? vv * cv + p * sv : vv * cv - p * sv;
                }
                Cb[(size_t)(row0 + r) * HIDD + col] = f2bf(vv);
            }
        }
}

// Output projection: fp32 C.
__global__ __launch_bounds__(256) void o_gemm(const short* __restrict__ Ab,
                                              const short* __restrict__ Bb,
                                              float* __restrict__ C) {
    __shared__ short As[128 * 64];
    __shared__ short Bs[128 * 64];
    const int tid = threadIdx.x;
    const int w = tid >> 6, l = tid & 63;
    const int lq = l & 15, lg = l >> 4;
    const int wr = w >> 1, wc = w & 1;
    const int bm = blockIdx.y * 128;
    const int bn = blockIdx.x * 128;

    f32x4 acc[4][4] = {};
    gemm_mainloop(Ab, Bb, As, Bs, acc, bm, bn, w, l, lq, lg, wr, wc);

#pragma unroll
    for (int m = 0; m < 4; ++m)
#pragma unroll
        for (int n = 0; n < 4; ++n) {
            const int row0 = bm + wr * 64 + m * 16 + lg * 4;
            const int col  = bn + wc * 64 + n * 16 + lq;
#pragma unroll
            for (int r = 0; r < 4; ++r)
                C[(size_t)(row0 + r) * HIDD + col] = acc[m][n][r];
        }
}

// ------------------------------------------------- MFMA differential flash --
// (unchanged from round 5 — validated)
#define KVB 64

__device__ __forceinline__ bf16x8 pack_pa(const float p0[4], const float p1[4]) {
    union { unsigned u[4]; bf16x8 v; } r;
    r.u[0] = pk2(p0[0], p0[1]);
    r.u[1] = pk2(p0[2], p0[3]);
    r.u[2] = pk2(p1[0], p1[1]);
    r.u[3] = pk2(p1[2], p1[3]);
    return r.v;
}

__device__ __forceinline__ void softmax_step(
        f32x4 sc[4], float& M, float& L, f32x4 O[8], bf16x8 pa[2],
        int t0, int qg, int lg, bool domask) {
#pragma unroll
    for (int sub = 0; sub < 4; ++sub)
#pragma unroll
        for (int r = 0; r < 4; ++r) {
            float s = sc[sub][r] * SCALE_F;
            if (domask) {
                int key = t0 + sub * 16 + lg * 4 + r;
                s = (key <= qg) ? s : -1e30f;
            }
            sc[sub][r] = s;
        }
    float mx = -1e30f;
#pragma unroll
    for (int sub = 0; sub < 4; ++sub) {
        float a01 = fmaxf(sc[sub][0], sc[sub][1]);
        float a23 = fmaxf(sc[sub][2], sc[sub][3]);
        mx = fmaxf(mx, fmaxf(a01, a23));
    }
    mx = fmaxf(mx, __shfl_xor(mx, 16));
    mx = fmaxf(mx, __shfl_xor(mx, 32));
    if (__ballot(mx > M + 8.f)) {           // defer-max (T13, THR=8)
        const float Mn = fmaxf(M, mx);
        const float a = __expf(M - Mn);
        M = Mn;
        L *= a;
        float ar[4];
#pragma unroll
        for (int r = 0; r < 4; ++r) ar[r] = __shfl(a, lg * 4 + r);
#pragma unroll
        for (int d = 0; d < 8; ++d) {
            O[d][0] *= ar[0]; O[d][1] *= ar[1]; O[d][2] *= ar[2]; O[d][3] *= ar[3];
        }
    }
    float p[4][4];
    float ps = 0.f;
#pragma unroll
    for (int sub = 0; sub < 4; ++sub) {
#pragma unroll
        for (int r = 0; r < 4; ++r) p[sub][r] = __expf(sc[sub][r] - M);
        ps += (p[sub][0] + p[sub][1]) + (p[sub][2] + p[sub][3]);
    }
    ps += __shfl_xor(ps, 16);
    ps += __shfl_xor(ps, 32);
    L += ps;
    pa[0] = pack_pa(p[0], p[1]);
    pa[1] = pack_pa(p[2], p[3]);
}

__global__ __launch_bounds__(256, 2) void flash_mfma(
        const short* __restrict__ Qb, const short* __restrict__ Kb,
        const short* __restrict__ Vb, const float* __restrict__ gnw,
        const float* __restrict__ lam_p, short* __restrict__ Hob) {
    __shared__ short Ksh[KVB * 128];   // row-major, 16B-group xor-swizzled
    __shared__ short VT[HDD * 72];     // VT[d][key], row stride 72 shorts

    const int tid = threadIdx.x;
    const int w  = tid >> 6;
    const int l  = tid & 63;
    const int lq = l & 15;
    const int lg = l >> 4;

    const int blk = blockIdx.x;
    const int bh  = blk & 31;
    const int bx  = 31 - (blk >> 5);      // heavy blocks first
    const int b = bh >> 4, h = bh & 15;
    const int s0 = bx * 64;
    const float lam = lam_p[0];

    const int qg = s0 + w * 16 + lq;
    const short* qrow = Qb + ((size_t)(b * SDIM + qg)) * HIDD + h * HDD;
    bf16x8 qf[2][2];
#pragma unroll
    for (int br = 0; br < 2; ++br)
#pragma unroll
        for (int ks = 0; ks < 2; ++ks)
            qf[br][ks] = *(const bf16x8*)(qrow + br * 64 + ks * 32 + lg * 8);

    int kkey[4], kcol[4];
#pragma unroll
    for (int i = 0; i < 4; ++i) {
        kkey[i] = w * 16 + i * 4 + lg;
        kcol[i] = (lq * 8) ^ ((kkey[i] & 7) << 3);
    }
    const int kp = tid & 31, dq = tid >> 5;

    const short* Kbase = Kb + ((size_t)(b * SDIM)) * HIDD + h * HDD;
    const short* Vbase = Vb + ((size_t)(b * SDIM)) * HIDD + h * HDD;

    float M1 = -1e30f, M2 = -1e30f, L1 = 0.f, L2 = 0.f;
    f32x4 O1[8] = {}; f32x4 O2[8] = {};

    const int ntmax = bx + 1;
    const int qmin = s0 + w * 16;
    const int ntw = (qmin >> 6) + 1;

    for (int t = 0; t < ntmax; ++t) {
        const size_t trow = (size_t)t * KVB * HIDD;
        __syncthreads();
#pragma unroll
        for (int i = 0; i < 4; ++i)
            gload_lds16(Kbase + trow + (size_t)kkey[i] * HIDD + kcol[i],
                        &Ksh[w * 2048 + i * 512]);
        {
            const short* v0 = Vbase + trow + (size_t)(2 * kp) * HIDD + dq * 16;
            const short* v1 = v0 + HIDD;
            bf16x8 v00 = *(const bf16x8*)v0;
            bf16x8 v01 = *(const bf16x8*)(v0 + 8);
            bf16x8 v10 = *(const bf16x8*)v1;
            bf16x8 v11 = *(const bf16x8*)(v1 + 8);
#pragma unroll
            for (int j = 0; j < 8; ++j) {
                unsigned ua = (unsigned)(unsigned short)v00[j] |
                              ((unsigned)(unsigned short)v10[j] << 16);
                *(unsigned*)&VT[(dq * 16 + j) * 72 + 2 * kp] = ua;
                unsigned ub = (unsigned)(unsigned short)v01[j] |
                              ((unsigned)(unsigned short)v11[j] << 16);
                *(unsigned*)&VT[(dq * 16 + 8 + j) * 72 + 2 * kp] = ub;
            }
        }
        __syncthreads();
        if (t >= ntw) continue;

        f32x4 sc1[4] = {}; f32x4 sc2[4] = {};
        const int rsw = (lq & 7) << 3;
#pragma unroll
        for (int sub = 0; sub < 4; ++sub) {
            const int rbase = (sub * 16 + lq) * 128;
            bf16x8 k00 = *(const bf16x8*)&Ksh[rbase + ((lg * 8) ^ rsw)];
            bf16x8 k01 = *(const bf16x8*)&Ksh[rbase + ((32 + lg * 8) ^ rsw)];
            bf16x8 k10 = *(const bf16x8*)&Ksh[rbase + ((64 + lg * 8) ^ rsw)];
            bf16x8 k11 = *(const bf16x8*)&Ksh[rbase + ((96 + lg * 8) ^ rsw)];
            sc1[sub] = MFMA16(k00, qf[0][0], sc1[sub]);
            sc1[sub] = MFMA16(k01, qf[0][1], sc1[sub]);
            sc2[sub] = MFMA16(k10, qf[1][0], sc2[sub]);
            sc2[sub] = MFMA16(k11, qf[1][1], sc2[sub]);
        }
        const int t0 = t * KVB;
        const bool domask = (t0 + KVB - 1 > qmin);
        bf16x8 pa1[2], pa2[2];
        softmax_step(sc1, M1, L1, O1, pa1, t0, qg, lg, domask);
        softmax_step(sc2, M2, L2, O2, pa2, t0, qg, lg, domask);

#pragma unroll
        for (int d0 = 0; d0 < 8; ++d0) {
            const short* vrow = &VT[(d0 * 16 + lq) * 72];
            bf16x4 a0 = *(const bf16x4*)&vrow[lg * 4];
            bf16x4 a1 = *(const bf16x4*)&vrow[16 + lg * 4];
            bf16x4 b0 = *(const bf16x4*)&vrow[32 + lg * 4];
            bf16x4 b1 = *(const bf16x4*)&vrow[48 + lg * 4];
            bf16x8 vb0 = __builtin_shufflevector(a0, a1, 0, 1, 2, 3, 4, 5, 6, 7);
            bf16x8 vb1 = __builtin_shufflevector(b0, b1, 0, 1, 2, 3, 4, 5, 6, 7);
            O1[d0] = MFMA16(pa1[0], vb0, O1[d0]);
            O1[d0] = MFMA16(pa1[1], vb1, O1[d0]);
            O2[d0] = MFMA16(pa2[0], vb0, O2[d0]);
            O2[d0] = MFMA16(pa2[1], vb1, O2[d0]);
        }
    }

    const float inv1 = 1.f / L1;
    const float inv2 = lam / L2;
    float i1[4], i2[4];
#pragma unroll
    for (int r = 0; r < 4; ++r) {
        i1[r] = __shfl(inv1, lg * 4 + r);
        i2[r] = __shfl(inv2, lg * 4 + r);
    }
    float gn[8];
#pragma unroll
    for (int d = 0; d < 8; ++d) gn[d] = gnw[d * 16 + lq];
    float od[8][4];
    float ss[4] = {0.f, 0.f, 0.f, 0.f};
#pragma unroll
    for (int d = 0; d < 8; ++d)
#pragma unroll
        for (int r = 0; r < 4; ++r) {
            float o = O1[d][r] * i1[r] - O2[d][r] * i2[r];
            od[d][r] = o;
            ss[r] += o * o;
        }
#pragma unroll
    for (int r = 0; r < 4; ++r) {
        ss[r] += __shfl_xor(ss[r], 1);
        ss[r] += __shfl_xor(ss[r], 2);
        ss[r] += __shfl_xor(ss[r], 4);
        ss[r] += __shfl_xor(ss[r], 8);
    }
#pragma unroll
    for (int r = 0; r < 4; ++r) {
        const float scal = rsqrtf(ss[r] * (1.0f / HDD) + EPS_F) * (1.0f - LAMBDA_INIT_F);
        const size_t orow = ((size_t)(b * SDIM + s0 + w * 16 + lg * 4 + r)) * HIDD + h * HDD;
#pragma unroll
        for (int d = 0; d < 8; ++d)
            Hob[orow + d * 16 + lq] = f2bf(od[d][r] * scal * gn[d]);
    }
}

// ----------------------------------------------------------------- launch ---
extern "C" void kernel_launch(void* const* d_in, const int* in_sizes, int n_in,
                              void* d_out, int out_size, void* d_ws, size_t ws_size,
                              hipStream_t stream) {
    const float* q   = (const float*)d_in[0];
    const float* k   = (const float*)d_in[1];
    const float* v   = (const float*)d_in[2];
    const float* Wq  = (const float*)d_in[3];
    const float* Wk  = (const float*)d_in[4];
    const float* Wv  = (const float*)d_in[5];
    const float* Wo  = (const float*)d_in[6];
    const float* lq1 = (const float*)d_in[7];
    const float* lk1 = (const float*)d_in[8];
    const float* lq2 = (const float*)d_in[9];
    const float* lk2 = (const float*)d_in[10];
    const float* gnw = (const float*)d_in[11];
    const float* cosE = (const float*)d_in[12];
    const float* sinE = (const float*)d_in[13];
    float* out = (float*)d_out;

    const size_t TEN = (size_t)BDIM * SDIM * HIDD;  // 8388608
    const int   WN  = HIDD * HIDD;                  // 4194304

    short* wsS = (short*)d_ws;
    short* Qb   = wsS;                  // 3x TEN projections
    short* Kb   = wsS + TEN;
    short* Vb   = wsS + 2 * TEN;
    short* xqkv = wsS + 3 * TEN;        // 3x TEN bf16 inputs; xq reused as Hob
    short* wb4  = wsS + 6 * TEN;        // 4x WN bf16 weights (Wq,Wk,Wv,Wo)
    float* lamp = (float*)(wsS + 6 * TEN + (size_t)4 * WN);
    short* Hob  = xqkv;                 // alias (xq dead after QKV GEMM)

    lambda_kernel<<<1, 64, 0, stream>>>(lq1, lk1, lq2, lk2, lamp);

    dim3 gx((int)(TEN / 8 / 256), 3);
    conv_x<<<gx, 256, 0, stream>>>(q, k, v, xqkv, (int)TEN);
    dim3 gw(WN / 8 / 256, 4);
    conv_w<<<gw, 256, 0, stream>>>(Wq, Wk, Wv, Wo, wb4, WN);

    dim3 gq(HIDD / 128, MTOT / 128, 3);
    qkv_gemm<<<gq, 256, 0, stream>>>(xqkv, xqkv + TEN, xqkv + 2 * TEN, wb4,
                                     Qb, Kb, Vb, cosE, sinE);

    flash_mfma<<<(SDIM / 64) * BDIM * NHH, 256, 0, stream>>>(Qb, Kb, Vb, gnw, lamp, Hob);

    dim3 go(HIDD / 128, MTOT / 128);
    o_gemm<<<go, 256, 0, stream>>>(Hob, wb4 + (size_t)3 * WN, out);
}

// Round 7
// 314.780 us; speedup vs baseline: 13.7004x; 1.0502x over previous
//
#include <hip/hip_runtime.h>
#include <math.h>

#define BDIM 2
#define SDIM 2048
#define HIDD 2048
#define NHH 16
#define HDD 128
#define QKDD 64
#define MTOT (BDIM*SDIM)   // 4096

constexpr float LAMBDA_INIT_F = 0.3555090675909693f;  // 0.8 - 0.6*exp(-0.3)
constexpr float EPS_F = 1e-6f;
constexpr float SCALE_F = 0.125f;                     // 1/sqrt(64)

typedef float f32x4 __attribute__((ext_vector_type(4)));
typedef short bf16x8 __attribute__((ext_vector_type(8)));
typedef short bf16x4 __attribute__((ext_vector_type(4)));

#define MFMA16(a, b, c) __builtin_amdgcn_mfma_f32_16x16x32_bf16((a), (b), (c), 0, 0, 0)

__device__ __forceinline__ short f2bf(float f) {
    unsigned u = __float_as_uint(f);
    u += 0x7FFFu + ((u >> 16) & 1u);   // RNE
    return (short)(u >> 16);
}
__device__ __forceinline__ unsigned pk2(float a, float b) {
    return (unsigned)(unsigned short)f2bf(a) | ((unsigned)(unsigned short)f2bf(b) << 16);
}

__device__ __forceinline__ void gload_lds16(const void* g, void* l) {
    __builtin_amdgcn_global_load_lds(
        (const __attribute__((address_space(1))) void*)g,
        (__attribute__((address_space(3))) void*)l, 16, 0, 0);
}
__device__ __forceinline__ void waitv8() { asm volatile("s_waitcnt vmcnt(8)" ::: "memory"); }
__device__ __forceinline__ void waitv0() { asm volatile("s_waitcnt vmcnt(0)" ::: "memory"); }
__device__ __forceinline__ void waitl0() { asm volatile("s_waitcnt lgkmcnt(0)" ::: "memory"); }
#define SBAR()   __builtin_amdgcn_s_barrier()
#define SCHEDB() __builtin_amdgcn_sched_barrier(0)

// ---------------------------------------------------------------- lambda ----
__global__ void lambda_kernel(const float* __restrict__ lq1, const float* __restrict__ lk1,
                              const float* __restrict__ lq2, const float* __restrict__ lk2,
                              float* __restrict__ lam_out) {
    int l = threadIdx.x;
    float d1 = lq1[l] * lk1[l] + lq1[l + 64] * lk1[l + 64];
    float d2 = lq2[l] * lk2[l] + lq2[l + 64] * lk2[l + 64];
#pragma unroll
    for (int o = 32; o > 0; o >>= 1) {
        d1 += __shfl_down(d1, o);
        d2 += __shfl_down(d2, o);
    }
    if (l == 0) lam_out[0] = expf(d1) - expf(d2) + LAMBDA_INIT_F;
}

// ---------------------------------------------------------------- convert ---
__global__ __launch_bounds__(256) void conv_x(const float* __restrict__ s0,
                                              const float* __restrict__ s1,
                                              const float* __restrict__ s2,
                                              short* __restrict__ dst, int n) {
    const float* src = (blockIdx.y == 0) ? s0 : (blockIdx.y == 1) ? s1 : s2;
    short* out = dst + (size_t)blockIdx.y * n;
    int i = (blockIdx.x * 256 + threadIdx.x) * 8;
    if (i >= n) return;
    float4 a = *(const float4*)&src[i];
    float4 b = *(const float4*)&src[i + 4];
    uint4 o;
    o.x = pk2(a.x, a.y); o.y = pk2(a.z, a.w);
    o.z = pk2(b.x, b.y); o.w = pk2(b.z, b.w);
    *(uint4*)&out[i] = o;
}
__global__ __launch_bounds__(256) void conv_w(const float* __restrict__ s0,
                                              const float* __restrict__ s1,
                                              const float* __restrict__ s2,
                                              const float* __restrict__ s3,
                                              short* __restrict__ dst, int n) {
    const float* src = (blockIdx.y == 0) ? s0 : (blockIdx.y == 1) ? s1
                     : (blockIdx.y == 2) ? s2 : s3;
    short* out = dst + (size_t)blockIdx.y * n;
    int i = (blockIdx.x * 256 + threadIdx.x) * 8;
    if (i >= n) return;
    float4 a = *(const float4*)&src[i];
    float4 b = *(const float4*)&src[i + 4];
    uint4 o;
    o.x = pk2(a.x, a.y); o.y = pk2(a.z, a.w);
    o.z = pk2(b.x, b.y); o.w = pk2(b.z, b.w);
    *(uint4*)&out[i] = o;
}

// ------------------------------------------------------------ bf16 GEMM -----
// C[M,N] = X[M,K](bf16) @ W[N,K]^T(bf16). 128x128 tile, BK=64, 4 waves (2x2).
// Double-buffered LDS + counted vmcnt pipeline (raw s_barrier, never drain-0
// in the main loop). LDS XOR-swizzled in 16B units (inverse folded into the
// global_load_lds source column; read-side XOR is (lq&7)<<3, constant).
#define GK 2048
// nt = GK/64 = 32 K-tiles, fixed.

__device__ __forceinline__ void gemm_mainloop(
        const short* __restrict__ X, const short* __restrict__ W,
        short* As, short* Bs, f32x4 acc[4][4],
        int bm, int bn, int w, int l, int lq, int lg, int wr, int wc) {
    const int scol = (((l & 7) ^ (l >> 3)) << 3);
    const int rsw  = (lq & 7) << 3;
    const short* aS[4]; const short* bS[4];
#pragma unroll
    for (int i = 0; i < 4; ++i) {
        const int c = w * 4 + i;
        aS[i] = X + (size_t)(bm + c * 8 + (l >> 3)) * GK + scol;
        bS[i] = W + (size_t)(bn + c * 8 + (l >> 3)) * GK + scol;
    }
    const int dOff = (w * 4) * 512;   // this wave's staging base (shorts)

    // ---- prologue: stage tiles 0 (buf0) and 1 (buf1) ----
#pragma unroll
    for (int i = 0; i < 4; ++i) {
        gload_lds16(aS[i], As + dOff + i * 512);
        gload_lds16(bS[i], Bs + dOff + i * 512);
    }
#pragma unroll
    for (int i = 0; i < 4; ++i) {
        gload_lds16(aS[i] + 64, As + 8192 + dOff + i * 512);
        gload_lds16(bS[i] + 64, Bs + 8192 + dOff + i * 512);
    }
    waitv8();   // tile0's 8 loads done (FIFO); tile1's 8 still in flight
    SBAR();

    for (int t = 0; t < 30; ++t) {
        const short* Ab = As + (t & 1) * 8192;
        const short* Bb = Bs + (t & 1) * 8192;
        bf16x8 a[4][2], b[4][2];
#pragma unroll
        for (int m = 0; m < 4; ++m)
#pragma unroll
            for (int kk = 0; kk < 2; ++kk)
                a[m][kk] = *(const bf16x8*)&Ab[(wr * 64 + m * 16 + lq) * 64 + ((kk * 32 + lg * 8) ^ rsw)];
#pragma unroll
        for (int n = 0; n < 4; ++n)
#pragma unroll
            for (int kk = 0; kk < 2; ++kk)
                b[n][kk] = *(const bf16x8*)&Bb[(wc * 64 + n * 16 + lq) * 64 + ((kk * 32 + lg * 8) ^ rsw)];
        waitl0(); SCHEDB();   // frags in regs; this wave done with buf[t&1]
        SBAR();               // ALL waves done with buf[t&1]
        {   // stage tile t+2 into buf[t&1]; loads fly under the MFMAs
            short* Ad = As + (t & 1) * 8192 + dOff;
            short* Bd = Bs + (t & 1) * 8192 + dOff;
            const short* aK = aS[0] + (t + 2) * 64;   // recompute per i below
            (void)aK;
#pragma unroll
            for (int i = 0; i < 4; ++i) {
                gload_lds16(aS[i] + (t + 2) * 64, Ad + i * 512);
                gload_lds16(bS[i] + (t + 2) * 64, Bd + i * 512);
            }
        }
        SCHEDB();             // keep stage-issue ahead of the MFMA cluster
#pragma unroll
        for (int kk = 0; kk < 2; ++kk)
#pragma unroll
            for (int m = 0; m < 4; ++m)
#pragma unroll
                for (int n = 0; n < 4; ++n)
                    acc[m][n] = MFMA16(a[m][kk], b[n][kk], acc[m][n]);
        waitv8();             // 16 outstanding -> oldest 8 (tile t+1) complete
        SBAR();
    }
    // ---- t = 30 (buf0): no stage, drain remaining ----
    {
        bf16x8 a[4][2], b[4][2];
#pragma unroll
        for (int m = 0; m < 4; ++m)
#pragma unroll
            for (int kk = 0; kk < 2; ++kk)
                a[m][kk] = *(const bf16x8*)&As[(wr * 64 + m * 16 + lq) * 64 + ((kk * 32 + lg * 8) ^ rsw)];
#pragma unroll
        for (int n = 0; n < 4; ++n)
#pragma unroll
            for (int kk = 0; kk < 2; ++kk)
                b[n][kk] = *(const bf16x8*)&Bs[(wc * 64 + n * 16 + lq) * 64 + ((kk * 32 + lg * 8) ^ rsw)];
        waitl0(); SCHEDB();
        SBAR();
#pragma unroll
        for (int kk = 0; kk < 2; ++kk)
#pragma unroll
            for (int m = 0; m < 4; ++m)
#pragma unroll
                for (int n = 0; n < 4; ++n)
                    acc[m][n] = MFMA16(a[m][kk], b[n][kk], acc[m][n]);
        waitv0();             // tile31 resident
        SBAR();
    }
    // ---- t = 31 (buf1) ----
    {
        bf16x8 a[4][2], b[4][2];
#pragma unroll
        for (int m = 0; m < 4; ++m)
#pragma unroll
            for (int kk = 0; kk < 2; ++kk)
                a[m][kk] = *(const bf16x8*)&As[8192 + (wr * 64 + m * 16 + lq) * 64 + ((kk * 32 + lg * 8) ^ rsw)];
#pragma unroll
        for (int n = 0; n < 4; ++n)
#pragma unroll
            for (int kk = 0; kk < 2; ++kk)
                b[n][kk] = *(const bf16x8*)&Bs[8192 + (wc * 64 + n * 16 + lq) * 64 + ((kk * 32 + lg * 8) ^ rsw)];
#pragma unroll
        for (int kk = 0; kk < 2; ++kk)
#pragma unroll
            for (int m = 0; m < 4; ++m)
#pragma unroll
                for (int n = 0; n < 4; ++n)
                    acc[m][n] = MFMA16(a[m][kk], b[n][kk], acc[m][n]);
    }
}

// Batched QKV projection: z=0 -> Q (RoPE), z=1 -> K (RoPE), z=2 -> V (plain).
__global__ __launch_bounds__(256) void qkv_gemm(
        const short* __restrict__ Xq, const short* __restrict__ Xk, const short* __restrict__ Xv,
        const short* __restrict__ Wb, short* __restrict__ Qb, short* __restrict__ Kb,
        short* __restrict__ Vb, const float* __restrict__ cosE, const float* __restrict__ sinE) {
    __shared__ short As[2 * 128 * 64];
    __shared__ short Bs[2 * 128 * 64];
    const int tid = threadIdx.x;
    const int w = tid >> 6, l = tid & 63;
    const int lq = l & 15, lg = l >> 4;
    const int wr = w >> 1, wc = w & 1;
    const int bm = blockIdx.y * 128;
    const int bn = blockIdx.x * 128;
    const int z  = blockIdx.z;

    const short* X = (z == 0) ? Xq : (z == 1) ? Xk : Xv;
    const short* W = Wb + (size_t)z * HIDD * HIDD;
    short* Cb      = (z == 0) ? Qb : (z == 1) ? Kb : Vb;

    f32x4 acc[4][4] = {};
    gemm_mainloop(X, W, As, Bs, acc, bm, bn, w, l, lq, lg, wr, wc);

    const bool dorope = (z < 2);
#pragma unroll
    for (int m = 0; m < 4; ++m)
#pragma unroll
        for (int n = 0; n < 4; ++n) {
            const int row0 = bm + wr * 64 + m * 16 + lg * 4;
            const int col  = bn + wc * 64 + n * 16 + lq;
#pragma unroll
            for (int r = 0; r < 4; ++r) {
                float vv = acc[m][n][r];
                if (dorope) {
                    const int s  = (row0 + r) & (SDIM - 1);
                    const int c6 = col & 63;
                    const float cv = cosE[s * HDD + c6];
                    const float sv = sinE[s * HDD + c6];
                    const float p = __shfl_xor(vv, 1);
                    vv = (col & 1) ? vv * cv + p * sv : vv * cv - p * sv;
                }
                Cb[(size_t)(row0 + r) * HIDD + col] = f2bf(vv);
            }
        }
}

// Output projection: fp32 C.
__global__ __launch_bounds__(256) void o_gemm(const short* __restrict__ Ab,
                                              const short* __restrict__ Bb,
                                              float* __restrict__ C) {
    __shared__ short As[2 * 128 * 64];
    __shared__ short Bs[2 * 128 * 64];
    const int tid = threadIdx.x;
    const int w = tid >> 6, l = tid & 63;
    const int lq = l & 15, lg = l >> 4;
    const int wr = w >> 1, wc = w & 1;
    const int bm = blockIdx.y * 128;
    const int bn = blockIdx.x * 128;

    f32x4 acc[4][4] = {};
    gemm_mainloop(Ab, Bb, As, Bs, acc, bm, bn, w, l, lq, lg, wr, wc);

#pragma unroll
    for (int m = 0; m < 4; ++m)
#pragma unroll
        for (int n = 0; n < 4; ++n) {
            const int row0 = bm + wr * 64 + m * 16 + lg * 4;
            const int col  = bn + wc * 64 + n * 16 + lq;
#pragma unroll
            for (int r = 0; r < 4; ++r)
                C[(size_t)(row0 + r) * HIDD + col] = acc[m][n][r];
        }
}

// ------------------------------------------------- MFMA differential flash --
// (round-5 validated structure + T5 setprio around MFMA clusters)
#define KVB 64

__device__ __forceinline__ bf16x8 pack_pa(const float p0[4], const float p1[4]) {
    union { unsigned u[4]; bf16x8 v; } r;
    r.u[0] = pk2(p0[0], p0[1]);
    r.u[1] = pk2(p0[2], p0[3]);
    r.u[2] = pk2(p1[0], p1[1]);
    r.u[3] = pk2(p1[2], p1[3]);
    return r.v;
}

__device__ __forceinline__ void softmax_step(
        f32x4 sc[4], float& M, float& L, f32x4 O[8], bf16x8 pa[2],
        int t0, int qg, int lg, bool domask) {
#pragma unroll
    for (int sub = 0; sub < 4; ++sub)
#pragma unroll
        for (int r = 0; r < 4; ++r) {
            float s = sc[sub][r] * SCALE_F;
            if (domask) {
                int key = t0 + sub * 16 + lg * 4 + r;
                s = (key <= qg) ? s : -1e30f;
            }
            sc[sub][r] = s;
        }
    float mx = -1e30f;
#pragma unroll
    for (int sub = 0; sub < 4; ++sub) {
        float a01 = fmaxf(sc[sub][0], sc[sub][1]);
        float a23 = fmaxf(sc[sub][2], sc[sub][3]);
        mx = fmaxf(mx, fmaxf(a01, a23));
    }
    mx = fmaxf(mx, __shfl_xor(mx, 16));
    mx = fmaxf(mx, __shfl_xor(mx, 32));
    if (__ballot(mx > M + 8.f)) {           // defer-max (T13, THR=8)
        const float Mn = fmaxf(M, mx);
        const float a = __expf(M - Mn);
        M = Mn;
        L *= a;
        float ar[4];
#pragma unroll
        for (int r = 0; r < 4; ++r) ar[r] = __shfl(a, lg * 4 + r);
#pragma unroll
        for (int d = 0; d < 8; ++d) {
            O[d][0] *= ar[0]; O[d][1] *= ar[1]; O[d][2] *= ar[2]; O[d][3] *= ar[3];
        }
    }
    float p[4][4];
    float ps = 0.f;
#pragma unroll
    for (int sub = 0; sub < 4; ++sub) {
#pragma unroll
        for (int r = 0; r < 4; ++r) p[sub][r] = __expf(sc[sub][r] - M);
        ps += (p[sub][0] + p[sub][1]) + (p[sub][2] + p[sub][3]);
    }
    ps += __shfl_xor(ps, 16);
    ps += __shfl_xor(ps, 32);
    L += ps;
    pa[0] = pack_pa(p[0], p[1]);
    pa[1] = pack_pa(p[2], p[3]);
}

__global__ __launch_bounds__(256, 2) void flash_mfma(
        const short* __restrict__ Qb, const short* __restrict__ Kb,
        const short* __restrict__ Vb, const float* __restrict__ gnw,
        const float* __restrict__ lam_p, short* __restrict__ Hob) {
    __shared__ short Ksh[KVB * 128];   // row-major, 16B-group xor-swizzled
    __shared__ short VT[HDD * 72];     // VT[d][key], row stride 72 shorts

    const int tid = threadIdx.x;
    const int w  = tid >> 6;
    const int l  = tid & 63;
    const int lq = l & 15;
    const int lg = l >> 4;

    const int blk = blockIdx.x;
    const int bh  = blk & 31;
    const int bx  = 31 - (blk >> 5);      // heavy blocks first
    const int b = bh >> 4, h = bh & 15;
    const int s0 = bx * 64;
    const float lam = lam_p[0];

    const int qg = s0 + w * 16 + lq;
    const short* qrow = Qb + ((size_t)(b * SDIM + qg)) * HIDD + h * HDD;
    bf16x8 qf[2][2];
#pragma unroll
    for (int br = 0; br < 2; ++br)
#pragma unroll
        for (int ks = 0; ks < 2; ++ks)
            qf[br][ks] = *(const bf16x8*)(qrow + br * 64 + ks * 32 + lg * 8);

    int kkey[4], kcol[4];
#pragma unroll
    for (int i = 0; i < 4; ++i) {
        kkey[i] = w * 16 + i * 4 + lg;
        kcol[i] = (lq * 8) ^ ((kkey[i] & 7) << 3);
    }
    const int kp = tid & 31, dq = tid >> 5;

    const short* Kbase = Kb + ((size_t)(b * SDIM)) * HIDD + h * HDD;
    const short* Vbase = Vb + ((size_t)(b * SDIM)) * HIDD + h * HDD;

    float M1 = -1e30f, M2 = -1e30f, L1 = 0.f, L2 = 0.f;
    f32x4 O1[8] = {}; f32x4 O2[8] = {};

    const int ntmax = bx + 1;
    const int qmin = s0 + w * 16;
    const int ntw = (qmin >> 6) + 1;

    for (int t = 0; t < ntmax; ++t) {
        const size_t trow = (size_t)t * KVB * HIDD;
        __syncthreads();
#pragma unroll
        for (int i = 0; i < 4; ++i)
            gload_lds16(Kbase + trow + (size_t)kkey[i] * HIDD + kcol[i],
                        &Ksh[w * 2048 + i * 512]);
        {
            const short* v0 = Vbase + trow + (size_t)(2 * kp) * HIDD + dq * 16;
            const short* v1 = v0 + HIDD;
            bf16x8 v00 = *(const bf16x8*)v0;
            bf16x8 v01 = *(const bf16x8*)(v0 + 8);
            bf16x8 v10 = *(const bf16x8*)v1;
            bf16x8 v11 = *(const bf16x8*)(v1 + 8);
#pragma unroll
            for (int j = 0; j < 8; ++j) {
                unsigned ua = (unsigned)(unsigned short)v00[j] |
                              ((unsigned)(unsigned short)v10[j] << 16);
                *(unsigned*)&VT[(dq * 16 + j) * 72 + 2 * kp] = ua;
                unsigned ub = (unsigned)(unsigned short)v01[j] |
                              ((unsigned)(unsigned short)v11[j] << 16);
                *(unsigned*)&VT[(dq * 16 + 8 + j) * 72 + 2 * kp] = ub;
            }
        }
        __syncthreads();
        if (t >= ntw) continue;

        f32x4 sc1[4] = {}; f32x4 sc2[4] = {};
        const int rsw = (lq & 7) << 3;
        __builtin_amdgcn_s_setprio(1);
#pragma unroll
        for (int sub = 0; sub < 4; ++sub) {
            const int rbase = (sub * 16 + lq) * 128;
            bf16x8 k00 = *(const bf16x8*)&Ksh[rbase + ((lg * 8) ^ rsw)];
            bf16x8 k01 = *(const bf16x8*)&Ksh[rbase + ((32 + lg * 8) ^ rsw)];
            bf16x8 k10 = *(const bf16x8*)&Ksh[rbase + ((64 + lg * 8) ^ rsw)];
            bf16x8 k11 = *(const bf16x8*)&Ksh[rbase + ((96 + lg * 8) ^ rsw)];
            sc1[sub] = MFMA16(k00, qf[0][0], sc1[sub]);
            sc1[sub] = MFMA16(k01, qf[0][1], sc1[sub]);
            sc2[sub] = MFMA16(k10, qf[1][0], sc2[sub]);
            sc2[sub] = MFMA16(k11, qf[1][1], sc2[sub]);
        }
        __builtin_amdgcn_s_setprio(0);
        const int t0 = t * KVB;
        const bool domask = (t0 + KVB - 1 > qmin);
        bf16x8 pa1[2], pa2[2];
        softmax_step(sc1, M1, L1, O1, pa1, t0, qg, lg, domask);
        softmax_step(sc2, M2, L2, O2, pa2, t0, qg, lg, domask);

        __builtin_amdgcn_s_setprio(1);
#pragma unroll
        for (int d0 = 0; d0 < 8; ++d0) {
            const short* vrow = &VT[(d0 * 16 + lq) * 72];
            bf16x4 a0 = *(const bf16x4*)&vrow[lg * 4];
            bf16x4 a1 = *(const bf16x4*)&vrow[16 + lg * 4];
            bf16x4 b0 = *(const bf16x4*)&vrow[32 + lg * 4];
            bf16x4 b1 = *(const bf16x4*)&vrow[48 + lg * 4];
            bf16x8 vb0 = __builtin_shufflevector(a0, a1, 0, 1, 2, 3, 4, 5, 6, 7);
            bf16x8 vb1 = __builtin_shufflevector(b0, b1, 0, 1, 2, 3, 4, 5, 6, 7);
            O1[d0] = MFMA16(pa1[0], vb0, O1[d0]);
            O1[d0] = MFMA16(pa1[1], vb1, O1[d0]);
            O2[d0] = MFMA16(pa2[0], vb0, O2[d0]);
            O2[d0] = MFMA16(pa2[1], vb1, O2[d0]);
        }
        __builtin_amdgcn_s_setprio(0);
    }

    const float inv1 = 1.f / L1;
    const float inv2 = lam / L2;
    float i1[4], i2[4];
#pragma unroll
    for (int r = 0; r < 4; ++r) {
        i1[r] = __shfl(inv1, lg * 4 + r);
        i2[r] = __shfl(inv2, lg * 4 + r);
    }
    float gn[8];
#pragma unroll
    for (int d = 0; d < 8; ++d) gn[d] = gnw[d * 16 + lq];
    float od[8][4];
    float ss[4] = {0.f, 0.f, 0.f, 0.f};
#pragma unroll
    for (int d = 0; d < 8; ++d)
#pragma unroll
        for (int r = 0; r < 4; ++r) {
            float o = O1[d][r] * i1[r] - O2[d][r] * i2[r];
            od[d][r] = o;
            ss[r] += o * o;
        }
#pragma unroll
    for (int r = 0; r < 4; ++r) {
        ss[r] += __shfl_xor(ss[r], 1);
        ss[r] += __shfl_xor(ss[r], 2);
        ss[r] += __shfl_xor(ss[r], 4);
        ss[r] += __shfl_xor(ss[r], 8);
    }
#pragma unroll
    for (int r = 0; r < 4; ++r) {
        const float scal = rsqrtf(ss[r] * (1.0f / HDD) + EPS_F) * (1.0f - LAMBDA_INIT_F);
        const size_t orow = ((size_t)(b * SDIM + s0 + w * 16 + lg * 4 + r)) * HIDD + h * HDD;
#pragma unroll
        for (int d = 0; d < 8; ++d)
            Hob[orow + d * 16 + lq] = f2bf(od[d][r] * scal * gn[d]);
    }
}

// ----------------------------------------------------------------- launch ---
extern "C" void kernel_launch(void* const* d_in, const int* in_sizes, int n_in,
                              void* d_out, int out_size, void* d_ws, size_t ws_size,
                              hipStream_t stream) {
    const float* q   = (const float*)d_in[0];
    const float* k   = (const float*)d_in[1];
    const float* v   = (const float*)d_in[2];
    const float* Wq  = (const float*)d_in[3];
    const float* Wk  = (const float*)d_in[4];
    const float* Wv  = (const float*)d_in[5];
    const float* Wo  = (const float*)d_in[6];
    const float* lq1 = (const float*)d_in[7];
    const float* lk1 = (const float*)d_in[8];
    const float* lq2 = (const float*)d_in[9];
    const float* lk2 = (const float*)d_in[10];
    const float* gnw = (const float*)d_in[11];
    const float* cosE = (const float*)d_in[12];
    const float* sinE = (const float*)d_in[13];
    float* out = (float*)d_out;

    const size_t TEN = (size_t)BDIM * SDIM * HIDD;  // 8388608
    const int   WN  = HIDD * HIDD;                  // 4194304

    short* wsS = (short*)d_ws;
    short* Qb   = wsS;                  // 3x TEN projections
    short* Kb   = wsS + TEN;
    short* Vb   = wsS + 2 * TEN;
    short* xqkv = wsS + 3 * TEN;        // 3x TEN bf16 inputs; xq reused as Hob
    short* wb4  = wsS + 6 * TEN;        // 4x WN bf16 weights (Wq,Wk,Wv,Wo)
    float* lamp = (float*)(wsS + 6 * TEN + (size_t)4 * WN);
    short* Hob  = xqkv;                 // alias (xq dead after QKV GEMM)

    lambda_kernel<<<1, 64, 0, stream>>>(lq1, lk1, lq2, lk2, lamp);

    dim3 gx((int)(TEN / 8 / 256), 3);
    conv_x<<<gx, 256, 0, stream>>>(q, k, v, xqkv, (int)TEN);
    dim3 gw(WN / 8 / 256, 4);
    conv_w<<<gw, 256, 0, stream>>>(Wq, Wk, Wv, Wo, wb4, WN);

    dim3 gq(HIDD / 128, MTOT / 128, 3);
    qkv_gemm<<<gq, 256, 0, stream>>>(xqkv, xqkv + TEN, xqkv + 2 * TEN, wb4,
                                     Qb, Kb, Vb, cosE, sinE);

    flash_mfma<<<(SDIM / 64) * BDIM * NHH, 256, 0, stream>>>(Qb, Kb, Vb, gnw, lamp, Hob);

    dim3 go(HIDD / 128, MTOT / 128);
    o_gemm<<<go, 256, 0, stream>>>(Hob, wb4 + (size_t)3 * WN, out);
}